// Round 1
// baseline (1840.993 us; speedup 1.0000x reference)
//
#include <hip/hip_runtime.h>
#include <math.h>

// BRIMCell forward, fp32 baseline.
// B=8192, N=8 units, H=D=256, NH_IN=1, DK_IN=16, DV_IN=32, NH_C=4, DK_C=8, DV_C=256.
// Pipeline per batch-chunk:
//  stage_a:   kL/vL/qL -> scores -> mask(top-k of null scores, tie-break by index)
//             -> probs -> inputs; builds Abuf = [hs | inputs] (n-major)
//  gemm<0>:   gates G = Abuf(Bc x 288) @ Wg(288 x 1024)   [packed: r_sum,z_sum,gx_n,gh_n]
//  gru:       hs_new = GRU(G, hs)
//  gemm<0>:   QKV = hs_new(Bc x 256) @ Wqkv(256 x 1088)   [q2|k2|v2]
//  attn:      per-batch 4-head 8x8 attention -> ctx (Bc x 1024, n-major)
//  gemm<1>:   out = mask ? ctx@Wout + hs_new : hs_old  (writes d_out directly)

#define B_TOT 8192
#define NU 8
#define HH 256
#define DD 256

__device__ __forceinline__ float sigm(float x){ return 1.0f/(1.0f+expf(-x)); }

// ---------- weight packing ----------
__global__ void pack_gates(const float* __restrict__ Wh2h, const float* __restrict__ Wx2h,
                           float* __restrict__ Wg)
{
    int idx = blockIdx.x*256 + threadIdx.x;
    const int total = 8*288*1024;
    if (idx >= total) return;
    int c = idx & 1023;
    int k = (idx >> 10) % 288;
    int n = idx / (288*1024);
    float v = 0.f;
    if (c < 512) {                       // r_sum (0..255), z_sum (256..511): gh + gx
        if (k < 256) v = Wh2h[((size_t)n*256 + k)*768 + c];
        else         v = Wx2h[((size_t)n*32 + (k-256))*768 + c];
    } else if (c < 768) {                // gx_n : only the inputs (k>=256) part, src col = c
        if (k >= 256) v = Wx2h[((size_t)n*32 + (k-256))*768 + c];
    } else {                             // gh_n : only hs part, src col = 512 + (c-768) = c-256
        if (k < 256) v = Wh2h[((size_t)n*256 + k)*768 + (c-256)];
    }
    Wg[idx] = v;
}

__global__ void pack_qkv(const float* __restrict__ Wq_, const float* __restrict__ Wk_,
                         const float* __restrict__ Wv_, float* __restrict__ Wqkv)
{
    int idx = blockIdx.x*256 + threadIdx.x;
    const int total = 8*256*1088;
    if (idx >= total) return;
    int c = idx % 1088;
    int k = (idx/1088) % 256;
    int n = idx / (1088*256);
    float v;
    if (c < 32)       v = Wq_[((size_t)n*256+k)*32 + c];
    else if (c < 64)  v = Wk_[((size_t)n*256+k)*32 + (c-32)];
    else              v = Wv_[((size_t)n*256+k)*1024 + (c-64)];
    Wqkv[idx] = v;
}

// ---------- stage A: input attention, mask, inputs; build Abuf ----------
__global__ __launch_bounds__(64) void stage_a(
    const float* __restrict__ x1, const float* __restrict__ x2,
    const float* __restrict__ hs,
    const float* __restrict__ Wkey, const float* __restrict__ bkey,
    const float* __restrict__ Wval, const float* __restrict__ bval,
    const float* __restrict__ Wq,
    float* __restrict__ Abuf, float* __restrict__ maskf,
    int Bc, int chunk0)
{
    int b  = blockIdx.x;
    int gb = chunk0 + b;
    int l  = threadIdx.x;

    __shared__ float vv[3][32];
    __shared__ float xk[3][16];
    __shared__ float qL[8][16];
    __shared__ float sc[8][3];
    __shared__ float pr[8][3];
    __shared__ float mk[8];

    const float* x1r = x1 + (size_t)gb*DD;
    const float* x2r = x2 + (size_t)gb*DD;

    // vL for slots 0,1 (slot 2 = bval, since x_null = 0)
    {
        int s = l >> 5, d = l & 31;
        const float* xr = s ? x2r : x1r;
        float acc = bval[d];
        for (int h = 0; h < DD; ++h) acc += xr[h]*Wval[h*32 + d];
        vv[s][d] = acc;
        if (l < 32) vv[2][l] = bval[l];
    }
    // kL for slots 0,1 (slot 2 = bkey)
    if (l < 32) {
        int s = l >> 4, k = l & 15;
        const float* xr = s ? x2r : x1r;
        float acc = bkey[k];
        for (int h = 0; h < DD; ++h) acc += xr[h]*Wkey[h*16 + k];
        xk[s][k] = acc;
    } else if (l < 48) {
        xk[2][l-32] = bkey[l-32];
    }
    // qL: 8 units x 16
    for (int it = 0; it < 2; ++it) {
        int idx = l + 64*it;
        int n = idx >> 4, k = idx & 15;
        const float* hr = hs + ((size_t)gb*NU + n)*HH;
        float acc = 0.f;
        for (int h = 0; h < HH; ++h) acc += hr[h]*Wq[((size_t)n*HH + h)*16 + k];
        qL[n][k] = acc;
    }
    __syncthreads();

    // scores[n][s] = qL[n].kL[s] * DK_IN^-0.5 (=0.25)
    if (l < 24) {
        int n = l/3, s = l%3;
        float acc = 0.f;
        for (int k = 0; k < 16; ++k) acc += qL[n][k]*xk[s][k];
        sc[n][s] = acc * 0.25f;
    }
    __syncthreads();

    // softmax over 3 slots
    if (l < 8) {
        float a0 = sc[l][0], a1 = sc[l][1], a2 = sc[l][2];
        float m  = fmaxf(a0, fmaxf(a1, a2));
        float e0 = expf(a0-m), e1 = expf(a1-m), e2 = expf(a2-m);
        float inv = 1.f/(e0+e1+e2);
        pr[l][0] = e0*inv; pr[l][1] = e1*inv; pr[l][2] = e2*inv;
    }
    __syncthreads();

    // mask: top (N-K_ACT)=4 of null scores get 0. jax top_k tie-break: lower index first.
    if (l < 8) {
        float sn = sc[l][2];
        int rank = 0;
        for (int m = 0; m < 8; ++m) {
            float sm = sc[m][2];
            if (sm > sn || (sm == sn && m < l)) rank++;
        }
        float mv = (rank < 4) ? 0.f : 1.f;
        mk[l] = mv;
        maskf[b*8 + l] = mv;
    }
    __syncthreads();

    // inputs[n][d] = mask[n] * sum_s probs[n][s]*vL[s][d]  -> Abuf[..][256+d]
    for (int it = 0; it < 4; ++it) {
        int idx = l + 64*it;
        int n = idx >> 5, d = idx & 31;
        float v = mk[n]*(pr[n][0]*vv[0][d] + pr[n][1]*vv[1][d] + pr[n][2]*vv[2][d]);
        Abuf[((size_t)n*Bc + b)*288 + 256 + d] = v;
    }
    // copy hs rows into Abuf[..][0..255]
    for (int it = 0; it < 32; ++it) {
        int idx = l + 64*it;          // 0..2047
        int n = idx >> 8, h = idx & 255;
        Abuf[((size_t)n*Bc + b)*288 + h] = hs[((size_t)gb*NU + n)*HH + h];
    }
}

// ---------- GRU elementwise ----------
__global__ void gru_kernel(const float* __restrict__ G, const float* __restrict__ hs,
                           float* __restrict__ hs_new, int Bc, int chunk0)
{
    int idx = blockIdx.x*256 + threadIdx.x;   // Bc*8*256 total
    int o = idx & 255;
    int n = (idx >> 8) & 7;
    int b = idx >> 11;
    const float* Gn = G + ((size_t)n*Bc + b)*1024;
    float rs  = Gn[o];
    float zs  = Gn[256 + o];
    float gxn = Gn[512 + o];
    float ghn = Gn[768 + o];
    float hold = hs[((size_t)(chunk0 + b)*NU + n)*HH + o];
    float r = sigm(rs), z = sigm(zs);
    float nn = tanhf(gxn + r*ghn);
    hs_new[((size_t)n*Bc + b)*HH + o] = nn + z*(hold - nn);
}

// ---------- per-batch 4-head attention over 8 units ----------
__global__ __launch_bounds__(64) void attn_kernel(
    const float* __restrict__ QKV, const float* __restrict__ maskf,
    float* __restrict__ ctx, int Bc)
{
    int b = blockIdx.x;
    int l = threadIdx.x;
    __shared__ float qk[8][64];    // per unit: q2(32) | k2(32)
    __shared__ float P[4][8][8];

    for (int it = 0; it < 8; ++it) {
        int idx = l + 64*it;
        int n = idx >> 6, c = idx & 63;
        qk[n][c] = QKV[((size_t)n*Bc + b)*1088 + c];
    }
    __syncthreads();

    for (int it = 0; it < 4; ++it) {
        int idx = l + 64*it;              // 0..255 -> (h,n,m)
        int h = idx >> 6, n = (idx >> 3) & 7, m = idx & 7;
        float s = 0.f;
        for (int dk = 0; dk < 8; ++dk) s += qk[n][h*8 + dk]*qk[m][32 + h*8 + dk];
        P[h][n][m] = s * 0.35355339059327373f;   // DK_C^-0.5
    }
    __syncthreads();

    if (l < 32) {
        int h = l >> 3, n = l & 7;
        float mx = -1e30f;
        for (int m = 0; m < 8; ++m) mx = fmaxf(mx, P[h][n][m]);
        float e[8], sum = 0.f;
        for (int m = 0; m < 8; ++m) { e[m] = expf(P[h][n][m]-mx); sum += e[m]; }
        float scl = maskf[b*8 + n] / sum;
        for (int m = 0; m < 8; ++m) P[h][n][m] = e[m]*scl;
    }
    __syncthreads();

    // ctx[n][h*256+d] = sum_m P[h][n][m] * v2[m][h*256+d]
    for (int i = 0; i < 16; ++i) {
        int col = l + 64*i;               // 0..1023
        int h = col >> 8;
        float acc[8] = {0,0,0,0,0,0,0,0};
        for (int m = 0; m < 8; ++m) {
            float v = QKV[((size_t)m*Bc + b)*1088 + 64 + col];
            #pragma unroll
            for (int n = 0; n < 8; ++n) acc[n] += P[h][n][m]*v;
        }
        #pragma unroll
        for (int n = 0; n < 8; ++n) ctx[((size_t)n*Bc + b)*1024 + col] = acc[n];
    }
}

// ---------- generic tiled fp32 GEMM: C(Bc x M) = A(Bc x K) @ W(K x M), batched over n ----------
// MODE 0: plain store. MODE 1: final epilogue (add hs_new, mask blend with hs_old, write d_out).
template<int MODE>
__global__ __launch_bounds__(256) void gemm_kernel(
    const float* __restrict__ A, const float* __restrict__ W, float* __restrict__ C,
    int Bc, int K, int M,
    const float* __restrict__ hs_new, const float* __restrict__ maskf,
    const float* __restrict__ hs_glob, float* __restrict__ outp, int chunk0)
{
    int n    = blockIdx.z;
    int row0 = blockIdx.x * 64;
    int col0 = blockIdx.y * 64;
    const float* Ab = A + (size_t)n * Bc * K;
    const float* Wb = W + (size_t)n * K * M;

    __shared__ float As[16][68];  // [kk][row], padded
    __shared__ float Ws[16][68];  // [kk][col]

    int tid = threadIdx.x;
    int tx = tid & 15, ty = tid >> 4;
    float acc[4][4] = {};

    for (int k0 = 0; k0 < K; k0 += 16) {
        #pragma unroll
        for (int i = 0; i < 4; ++i) {
            int e = tid + 256*i;              // 0..1023
            int r = e >> 4, kk = e & 15;
            As[kk][r] = Ab[(size_t)(row0 + r)*K + (k0 + kk)];
        }
        #pragma unroll
        for (int i = 0; i < 4; ++i) {
            int e = tid + 256*i;
            int kk = e >> 6, c = e & 63;
            Ws[kk][c] = Wb[(size_t)(k0 + kk)*M + (col0 + c)];
        }
        __syncthreads();
        #pragma unroll
        for (int kk = 0; kk < 16; ++kk) {
            float a[4], w[4];
            #pragma unroll
            for (int i = 0; i < 4; ++i) a[i] = As[kk][ty*4 + i];
            #pragma unroll
            for (int j = 0; j < 4; ++j) w[j] = Ws[kk][tx*4 + j];
            #pragma unroll
            for (int i = 0; i < 4; ++i)
                #pragma unroll
                for (int j = 0; j < 4; ++j)
                    acc[i][j] += a[i]*w[j];
        }
        __syncthreads();
    }

    if (MODE == 0) {
        float* Cb = C + (size_t)n * Bc * M;
        #pragma unroll
        for (int i = 0; i < 4; ++i)
            #pragma unroll
            for (int j = 0; j < 4; ++j)
                Cb[(size_t)(row0 + ty*4 + i)*M + col0 + tx*4 + j] = acc[i][j];
    } else {
        // M == 256 (o), rows are batch-in-chunk
        #pragma unroll
        for (int i = 0; i < 4; ++i) {
            int b = row0 + ty*4 + i;
            float mkv = maskf[b*8 + n];
            size_t gi = ((size_t)(chunk0 + b)*NU + n)*HH;
            #pragma unroll
            for (int j = 0; j < 4; ++j) {
                int o = col0 + tx*4 + j;
                float v;
                if (mkv != 0.f) v = acc[i][j] + hs_new[((size_t)n*Bc + b)*HH + o];
                else            v = hs_glob[gi + o];
                outp[gi + o] = v;
            }
        }
    }
}

extern "C" void kernel_launch(void* const* d_in, const int* in_sizes, int n_in,
                              void* d_out, int out_size, void* d_ws, size_t ws_size,
                              hipStream_t stream)
{
    const float* x1   = (const float*)d_in[0];
    const float* x2   = (const float*)d_in[1];
    const float* hs   = (const float*)d_in[2];
    const float* Wkey = (const float*)d_in[3];
    const float* bkey = (const float*)d_in[4];
    const float* Wval = (const float*)d_in[5];
    const float* bval = (const float*)d_in[6];
    const float* Wq   = (const float*)d_in[7];
    const float* Wq_  = (const float*)d_in[8];
    const float* Wk_  = (const float*)d_in[9];
    const float* Wv_  = (const float*)d_in[10];
    const float* Wout = (const float*)d_in[11];
    const float* Wx2h = (const float*)d_in[12];
    const float* Wh2h = (const float*)d_in[13];
    float* out = (float*)d_out;

    // workspace carve-out
    char* ws = (char*)d_ws;
    size_t off = 0;
    auto alloc = [&](size_t bytes) -> float* {
        float* p = (float*)(ws + off);
        off = (off + bytes + 255) & ~(size_t)255;
        return p;
    };
    float* Wg   = alloc((size_t)8*288*1024*4);
    float* Wqkv = alloc((size_t)8*256*1088*4);
    size_t persist = off;

    // pick chunk size that fits ws: per-batch floats =
    // Abuf 2304 + mask 8 + G 8192 + hs_new 2048 + QKV 8704 + ctx 8192 = 29448
    int Bc = B_TOT;
    while (Bc > 64) {
        size_t per = (size_t)Bc * 29448ull * 4ull + 8192;
        if (persist + per <= ws_size) break;
        Bc >>= 1;
    }
    float* Abuf   = alloc((size_t)8*Bc*288*4);
    float* maskf  = alloc((size_t)Bc*8*4);
    float* G      = alloc((size_t)8*Bc*1024*4);
    float* hs_new = alloc((size_t)8*Bc*256*4);
    float* QKV    = alloc((size_t)8*Bc*1088*4);
    float* ctx    = alloc((size_t)8*Bc*1024*4);

    pack_gates<<<(8*288*1024 + 255)/256, 256, 0, stream>>>(Wh2h, Wx2h, Wg);
    pack_qkv  <<<(8*256*1088 + 255)/256, 256, 0, stream>>>(Wq_, Wk_, Wv_, Wqkv);

    for (int c0 = 0; c0 < B_TOT; c0 += Bc) {
        stage_a<<<Bc, 64, 0, stream>>>(x1, x2, hs, Wkey, bkey, Wval, bval, Wq,
                                       Abuf, maskf, Bc, c0);
        dim3 g1(Bc/64, 1024/64, 8);
        gemm_kernel<0><<<g1, 256, 0, stream>>>(Abuf, Wg, G, Bc, 288, 1024,
                                               nullptr, nullptr, nullptr, nullptr, 0);
        gru_kernel<<<Bc*8, 256, 0, stream>>>(G, hs, hs_new, Bc, c0);
        dim3 g2(Bc/64, 1088/64, 8);
        gemm_kernel<0><<<g2, 256, 0, stream>>>(hs_new, Wqkv, QKV, Bc, 256, 1088,
                                               nullptr, nullptr, nullptr, nullptr, 0);
        attn_kernel<<<Bc, 64, 0, stream>>>(QKV, maskf, ctx, Bc);
        dim3 g3(Bc/64, 256/64, 8);
        gemm_kernel<1><<<g3, 256, 0, stream>>>(ctx, Wout, nullptr, Bc, 1024, 256,
                                               hs_new, maskf, hs, out, c0);
    }
}

// Round 2
// 722.942 us; speedup vs baseline: 2.5465x; 2.5465x over previous
//
#include <hip/hip_runtime.h>
#include <math.h>

// BRIMCell forward — bf16 MFMA GEMMs, fp32 elsewhere.
// B=8192, N=8, H=D=256, NH_IN=1, DK_IN=16, DV_IN=32, NH_C=4, DK_C=8, DV_C=256.

#define B_TOT 8192
#define NU 8
#define HH 256
#define DD 256

typedef __attribute__((ext_vector_type(8))) short bf16x8;
typedef __attribute__((ext_vector_type(4))) float f32x4;

__device__ __forceinline__ float sigm(float x){ return 1.0f/(1.0f+expf(-x)); }

__device__ __forceinline__ unsigned short f2bf(float f){
    union { float f; unsigned int u; } v; v.f = f;
    unsigned int r = v.u + 0x7fffu + ((v.u >> 16) & 1u);
    return (unsigned short)(r >> 16);
}
__device__ __forceinline__ float bf2f(unsigned short h){
    union { unsigned int u; float f; } v; v.u = ((unsigned int)h) << 16;
    return v.f;
}

// ---------- weight packing (transposed [n][col][k], bf16) ----------
__global__ void pack_gates(const float* __restrict__ Wh2h, const float* __restrict__ Wx2h,
                           unsigned short* __restrict__ Wg)
{
    int idx = blockIdx.x*256 + threadIdx.x;
    const int total = 8*1024*288;
    if (idx >= total) return;
    int k = idx % 288;
    int c = (idx / 288) % 1024;
    int n = idx / (288*1024);
    float v = 0.f;
    if (c < 512) {                       // r_sum / z_sum: gh + gx parts
        v = (k < 256) ? Wh2h[((size_t)n*256 + k)*768 + c]
                      : Wx2h[((size_t)n*32 + (k-256))*768 + c];
    } else if (c < 768) {                // gx_n: inputs rows only
        if (k >= 256) v = Wx2h[((size_t)n*32 + (k-256))*768 + c];
    } else {                             // gh_n: hs rows only, src col c-256
        if (k < 256)  v = Wh2h[((size_t)n*256 + k)*768 + (c-256)];
    }
    Wg[idx] = f2bf(v);
}

__global__ void pack_qkv(const float* __restrict__ Wq_, const float* __restrict__ Wk_,
                         const float* __restrict__ Wv_, unsigned short* __restrict__ Wqkv)
{
    int idx = blockIdx.x*256 + threadIdx.x;
    const int total = 8*1152*256;
    if (idx >= total) return;
    int k = idx % 256;
    int c = (idx / 256) % 1152;
    int n = idx / (256*1152);
    float v = 0.f;
    if (c < 32)        v = Wq_[((size_t)n*256+k)*32 + c];
    else if (c < 64)   v = Wk_[((size_t)n*256+k)*32 + (c-32)];
    else if (c < 1088) v = Wv_[((size_t)n*256+k)*1024 + (c-64)];
    Wqkv[idx] = f2bf(v);
}

__global__ void pack_out(const float* __restrict__ Wout, unsigned short* __restrict__ Wt)
{
    int idx = blockIdx.x*256 + threadIdx.x;
    const int total = 8*256*1024;
    if (idx >= total) return;
    int k = idx % 1024;
    int c = (idx / 1024) % 256;
    int n = idx / (1024*256);
    Wt[idx] = f2bf(Wout[((size_t)n*1024 + k)*256 + c]);
}

// ---------- stage A: input attention, mask, inputs (bf16) ----------
__global__ __launch_bounds__(64) void stage_a(
    const float* __restrict__ x1, const float* __restrict__ x2,
    const float* __restrict__ hs,
    const float* __restrict__ Wkey, const float* __restrict__ bkey,
    const float* __restrict__ Wval, const float* __restrict__ bval,
    const float* __restrict__ Wq,
    unsigned short* __restrict__ inputs, float* __restrict__ maskf,
    int Bc, int chunk0)
{
    int b  = blockIdx.x;
    int gb = chunk0 + b;
    int l  = threadIdx.x;

    __shared__ float vv[3][32];
    __shared__ float xk[3][16];
    __shared__ float qL[8][16];
    __shared__ float sc[8][3];
    __shared__ float pr[8][3];
    __shared__ float mk[8];

    const float* x1r = x1 + (size_t)gb*DD;
    const float* x2r = x2 + (size_t)gb*DD;

    {
        int s = l >> 5, d = l & 31;
        const float* xr = s ? x2r : x1r;
        float acc = bval[d];
        for (int h = 0; h < DD; ++h) acc += xr[h]*Wval[h*32 + d];
        vv[s][d] = acc;
        if (l < 32) vv[2][l] = bval[l];
    }
    if (l < 32) {
        int s = l >> 4, k = l & 15;
        const float* xr = s ? x2r : x1r;
        float acc = bkey[k];
        for (int h = 0; h < DD; ++h) acc += xr[h]*Wkey[h*16 + k];
        xk[s][k] = acc;
    } else if (l < 48) {
        xk[2][l-32] = bkey[l-32];
    }
    for (int it = 0; it < 2; ++it) {
        int idx = l + 64*it;
        int n = idx >> 4, k = idx & 15;
        const float* hr = hs + ((size_t)gb*NU + n)*HH;
        float acc = 0.f;
        for (int h = 0; h < HH; ++h) acc += hr[h]*Wq[((size_t)n*HH + h)*16 + k];
        qL[n][k] = acc;
    }
    __syncthreads();

    if (l < 24) {
        int n = l/3, s = l%3;
        float acc = 0.f;
        for (int k = 0; k < 16; ++k) acc += qL[n][k]*xk[s][k];
        sc[n][s] = acc * 0.25f;
    }
    __syncthreads();

    if (l < 8) {
        float a0 = sc[l][0], a1 = sc[l][1], a2 = sc[l][2];
        float m  = fmaxf(a0, fmaxf(a1, a2));
        float e0 = expf(a0-m), e1 = expf(a1-m), e2 = expf(a2-m);
        float inv = 1.f/(e0+e1+e2);
        pr[l][0] = e0*inv; pr[l][1] = e1*inv; pr[l][2] = e2*inv;
    }
    __syncthreads();

    if (l < 8) {
        float sn = sc[l][2];
        int rank = 0;
        for (int m = 0; m < 8; ++m) {
            float sm = sc[m][2];
            if (sm > sn || (sm == sn && m < l)) rank++;
        }
        float mv = (rank < 4) ? 0.f : 1.f;
        mk[l] = mv;
        maskf[b*8 + l] = mv;
    }
    __syncthreads();

    for (int it = 0; it < 4; ++it) {
        int idx = l + 64*it;
        int n = idx >> 5, d = idx & 31;
        float v = mk[n]*(pr[n][0]*vv[0][d] + pr[n][1]*vv[1][d] + pr[n][2]*vv[2][d]);
        inputs[((size_t)n*Bc + b)*32 + d] = f2bf(v);
    }
}

// ---------- GRU elementwise ----------
__global__ void gru_kernel(const float* __restrict__ G, const float* __restrict__ hs,
                           float* __restrict__ hsn, unsigned short* __restrict__ hsnb,
                           int Bc, int chunk0)
{
    int idx = blockIdx.x*256 + threadIdx.x;
    int o = idx & 255;
    int n = (idx >> 8) & 7;
    int b = idx >> 11;
    const float* Gn = G + ((size_t)n*Bc + b)*1024;
    float rs  = Gn[o];
    float zs  = Gn[256 + o];
    float gxn = Gn[512 + o];
    float ghn = Gn[768 + o];
    float hold = hs[((size_t)(chunk0 + b)*NU + n)*HH + o];
    float r = sigm(rs), z = sigm(zs);
    float nn = tanhf(gxn + r*ghn);
    float h = nn + z*(hold - nn);
    hsn [((size_t)n*Bc + b)*256 + o] = h;
    hsnb[((size_t)n*Bc + b)*256 + o] = f2bf(h);
}

// ---------- per-batch 4-head attention over 8 units ----------
__global__ __launch_bounds__(64) void attn_kernel(
    const unsigned short* __restrict__ QKV, const float* __restrict__ maskf,
    unsigned short* __restrict__ ctx, int Bc)
{
    int b = blockIdx.x;
    int l = threadIdx.x;
    __shared__ float qk[8][64];
    __shared__ float P[4][8][8];

    for (int it = 0; it < 8; ++it) {
        int idx = l + 64*it;
        int n = idx >> 6, c = idx & 63;
        qk[n][c] = bf2f(QKV[((size_t)n*Bc + b)*1152 + c]);
    }
    __syncthreads();

    for (int it = 0; it < 4; ++it) {
        int idx = l + 64*it;
        int h = idx >> 6, n = (idx >> 3) & 7, m = idx & 7;
        float s = 0.f;
        for (int dk = 0; dk < 8; ++dk) s += qk[n][h*8 + dk]*qk[m][32 + h*8 + dk];
        P[h][n][m] = s * 0.35355339059327373f;
    }
    __syncthreads();

    if (l < 32) {
        int h = l >> 3, n = l & 7;
        float mx = -1e30f;
        for (int m = 0; m < 8; ++m) mx = fmaxf(mx, P[h][n][m]);
        float e[8], sum = 0.f;
        for (int m = 0; m < 8; ++m) { e[m] = expf(P[h][n][m]-mx); sum += e[m]; }
        float scl = maskf[b*8 + n] / sum;
        for (int m = 0; m < 8; ++m) P[h][n][m] = e[m]*scl;
    }
    __syncthreads();

    #pragma unroll
    for (int it = 0; it < 2; ++it) {
        int colb = (l + 64*it)*8;      // 8 consecutive v-cols
        int h = colb >> 8;
        float acc[8][8];
        #pragma unroll
        for (int n = 0; n < 8; ++n)
            #pragma unroll
            for (int c = 0; c < 8; ++c) acc[n][c] = 0.f;
        for (int m = 0; m < 8; ++m) {
            bf16x8 v8 = *(const bf16x8*)&QKV[((size_t)m*Bc + b)*1152 + 64 + colb];
            float vf[8];
            #pragma unroll
            for (int c = 0; c < 8; ++c) vf[c] = bf2f((unsigned short)v8[c]);
            #pragma unroll
            for (int n = 0; n < 8; ++n) {
                float p = P[h][n][m];
                #pragma unroll
                for (int c = 0; c < 8; ++c) acc[n][c] += p*vf[c];
            }
        }
        #pragma unroll
        for (int n = 0; n < 8; ++n) {
            bf16x8 o;
            #pragma unroll
            for (int c = 0; c < 8; ++c) o[c] = (short)f2bf(acc[n][c]);
            *(bf16x8*)&ctx[((size_t)n*Bc + b)*1024 + colb] = o;
        }
    }
}

// ---------- MFMA GEMM: C(Bc x M) = A(Bc x K) @ W(K x M), batched over n ----------
// MODE 0: gates  — A from hs(fp32, k<256) + inputs(bf16), C -> G fp32 (M=1024)
// MODE 1: qkv    — A = hsn_bf16, C -> QKV bf16 (M=1152)
// MODE 2: out    — A = ctx bf16, epilogue add hsn + mask blend, write d_out fp32 (M=256)
template<int MODE>
__global__ __launch_bounds__(256) void gemm_mfma(
    const float* __restrict__ hs_src,
    const unsigned short* __restrict__ Abf,
    const unsigned short* __restrict__ Wp,
    float* __restrict__ Cf, unsigned short* __restrict__ Cb,
    int Bc, int K, int M,
    const float* __restrict__ hsn_f32, const float* __restrict__ maskf,
    const float* __restrict__ hs_glob, float* __restrict__ outp, int c0)
{
    int n    = blockIdx.z;
    int row0 = blockIdx.x * 128;
    int col0 = blockIdx.y * 128;

    __shared__ unsigned short As[128*40];  // [row][k] stride 40 ushorts (80B)
    __shared__ unsigned short Ws[128*40];  // [col][k]

    int t = threadIdx.x;
    int l = t & 63, w = t >> 6;
    int wr = (w >> 1) * 64, wc = (w & 1) * 64;
    int lr = l & 15, lk = l >> 4;
    int srow = t >> 1, sseg = t & 1;       // staging: 128 rows x 2 halves of 16 k

    f32x4 acc[4][4];
    #pragma unroll
    for (int i = 0; i < 4; ++i)
        #pragma unroll
        for (int j = 0; j < 4; ++j)
            acc[i][j] = (f32x4){0.f, 0.f, 0.f, 0.f};

    for (int k0 = 0; k0 < K; k0 += 32) {
        bf16x8 u0, u1;
        if (MODE == 0 && k0 < 256) {
            const float* src = hs_src + (((size_t)(c0 + row0 + srow))*NU + n)*HH + k0 + sseg*16;
            float tmp[16];
            #pragma unroll
            for (int q = 0; q < 4; ++q) *(float4*)&tmp[q*4] = ((const float4*)src)[q];
            #pragma unroll
            for (int q = 0; q < 8; ++q) {
                u0[q] = (short)f2bf(tmp[q]);
                u1[q] = (short)f2bf(tmp[8+q]);
            }
        } else {
            const unsigned short* src;
            if (MODE == 0) src = Abf + ((size_t)n*Bc + row0 + srow)*32 + sseg*16;       // k0==256
            else           src = Abf + ((size_t)n*Bc + row0 + srow)*(size_t)K + k0 + sseg*16;
            u0 = ((const bf16x8*)src)[0];
            u1 = ((const bf16x8*)src)[1];
        }
        *(bf16x8*)&As[srow*40 + sseg*16]     = u0;
        *(bf16x8*)&As[srow*40 + sseg*16 + 8] = u1;
        {
            const unsigned short* src = Wp + ((size_t)n*M + col0 + srow)*(size_t)K + k0 + sseg*16;
            bf16x8 w0 = ((const bf16x8*)src)[0];
            bf16x8 w1 = ((const bf16x8*)src)[1];
            *(bf16x8*)&Ws[srow*40 + sseg*16]     = w0;
            *(bf16x8*)&Ws[srow*40 + sseg*16 + 8] = w1;
        }
        __syncthreads();

        bf16x8 a[4], bfr[4];
        #pragma unroll
        for (int i = 0; i < 4; ++i) a[i]   = *(const bf16x8*)&As[(wr + i*16 + lr)*40 + lk*8];
        #pragma unroll
        for (int j = 0; j < 4; ++j) bfr[j] = *(const bf16x8*)&Ws[(wc + j*16 + lr)*40 + lk*8];
        #pragma unroll
        for (int i = 0; i < 4; ++i)
            #pragma unroll
            for (int j = 0; j < 4; ++j)
                acc[i][j] = __builtin_amdgcn_mfma_f32_16x16x32_bf16(a[i], bfr[j], acc[i][j], 0, 0, 0);
        __syncthreads();
    }

    #pragma unroll
    for (int i = 0; i < 4; ++i) {
        int rbase = row0 + wr + i*16 + lk*4;
        #pragma unroll
        for (int j = 0; j < 4; ++j) {
            int c = col0 + wc + j*16 + lr;
            #pragma unroll
            for (int reg = 0; reg < 4; ++reg) {
                int r = rbase + reg;
                float v = acc[i][j][reg];
                if (MODE == 0) {
                    Cf[((size_t)n*Bc + r)*(size_t)M + c] = v;
                } else if (MODE == 1) {
                    Cb[((size_t)n*Bc + r)*(size_t)M + c] = f2bf(v);
                } else {
                    float mkv = maskf[r*8 + n];
                    size_t gi = (((size_t)(c0 + r))*NU + n)*HH + c;
                    float o = (mkv != 0.f) ? (v + hsn_f32[((size_t)n*Bc + r)*HH + c])
                                           : hs_glob[gi];
                    outp[gi] = o;
                }
            }
        }
    }
}

extern "C" void kernel_launch(void* const* d_in, const int* in_sizes, int n_in,
                              void* d_out, int out_size, void* d_ws, size_t ws_size,
                              hipStream_t stream)
{
    const float* x1   = (const float*)d_in[0];
    const float* x2   = (const float*)d_in[1];
    const float* hs   = (const float*)d_in[2];
    const float* Wkey = (const float*)d_in[3];
    const float* bkey = (const float*)d_in[4];
    const float* Wval = (const float*)d_in[5];
    const float* bval = (const float*)d_in[6];
    const float* Wq   = (const float*)d_in[7];
    const float* Wq_  = (const float*)d_in[8];
    const float* Wk_  = (const float*)d_in[9];
    const float* Wv_  = (const float*)d_in[10];
    const float* Wout = (const float*)d_in[11];
    const float* Wx2h = (const float*)d_in[12];
    const float* Wh2h = (const float*)d_in[13];
    float* out = (float*)d_out;

    char* ws = (char*)d_ws;
    size_t off = 0;
    auto alloc = [&](size_t bytes) -> void* {
        void* p = (void*)(ws + off);
        off = (off + bytes + 255) & ~(size_t)255;
        return p;
    };
    unsigned short* Wg    = (unsigned short*)alloc((size_t)8*1024*288*2);
    unsigned short* Wqkv  = (unsigned short*)alloc((size_t)8*1152*256*2);
    unsigned short* WoutT = (unsigned short*)alloc((size_t)8*256*1024*2);
    size_t persist = off;

    // per-batch ws bytes: inputs 512 + mask 32 + G 32768 + hsn 8192 + hsnb 4096
    //                   + QKV 18432 + ctx 16384 = 80416
    int Bc = B_TOT;
    while (Bc > 128) {
        size_t need = persist + (size_t)Bc*80416ull + 65536ull;
        if (need <= ws_size) break;
        Bc >>= 1;
    }
    unsigned short* inputs = (unsigned short*)alloc((size_t)8*Bc*32*2);
    float*          maskf  = (float*)         alloc((size_t)Bc*8*4);
    float*          G      = (float*)         alloc((size_t)8*Bc*1024*4);
    float*          hsn    = (float*)         alloc((size_t)8*Bc*256*4);
    unsigned short* hsnb   = (unsigned short*)alloc((size_t)8*Bc*256*2);
    unsigned short* QKV    = (unsigned short*)alloc((size_t)8*Bc*1152*2);
    unsigned short* ctx    = (unsigned short*)alloc((size_t)8*Bc*1024*2);

    pack_gates<<<(8*1024*288 + 255)/256, 256, 0, stream>>>(Wh2h, Wx2h, Wg);
    pack_qkv  <<<(8*1152*256 + 255)/256, 256, 0, stream>>>(Wq_, Wk_, Wv_, Wqkv);
    pack_out  <<<(8*256*1024 + 255)/256, 256, 0, stream>>>(Wout, WoutT);

    for (int c0 = 0; c0 < B_TOT; c0 += Bc) {
        stage_a<<<Bc, 64, 0, stream>>>(x1, x2, hs, Wkey, bkey, Wval, bval, Wq,
                                       inputs, maskf, Bc, c0);
        dim3 g1(Bc/128, 1024/128, 8);
        gemm_mfma<0><<<g1, 256, 0, stream>>>(hs, inputs, Wg, G, nullptr,
                                             Bc, 288, 1024,
                                             nullptr, nullptr, nullptr, nullptr, c0);
        gru_kernel<<<Bc*8, 256, 0, stream>>>(G, hs, hsn, hsnb, Bc, c0);
        dim3 g2(Bc/128, 1152/128, 8);
        gemm_mfma<1><<<g2, 256, 0, stream>>>(nullptr, hsnb, Wqkv, nullptr, QKV,
                                             Bc, 256, 1152,
                                             nullptr, nullptr, nullptr, nullptr, c0);
        attn_kernel<<<Bc, 64, 0, stream>>>(QKV, maskf, ctx, Bc);
        dim3 g3(Bc/128, 256/128, 8);
        gemm_mfma<2><<<g3, 256, 0, stream>>>(nullptr, ctx, WoutT, nullptr, nullptr,
                                             Bc, 1024, 256,
                                             hsn, maskf, hs, out, c0);
    }
}

// Round 3
// 565.867 us; speedup vs baseline: 3.2534x; 1.2776x over previous
//
#include <hip/hip_runtime.h>
#include <math.h>

// BRIMCell forward — bf16 MFMA GEMMs (dbuf+prefetch+swizzle, n->XCD), fused GRU.
// B=8192, N=8, H=D=256.

#define B_TOT 8192
#define NU 8
#define HH 256

typedef __attribute__((ext_vector_type(8))) short bf16x8;
typedef __attribute__((ext_vector_type(4))) float f32x4;

__device__ __forceinline__ float sigm(float x){ return 1.0f/(1.0f+expf(-x)); }

__device__ __forceinline__ unsigned short f2bf(float f){
    union { float f; unsigned int u; } v; v.f = f;
    unsigned int r = v.u + 0x7fffu + ((v.u >> 16) & 1u);
    return (unsigned short)(r >> 16);
}
__device__ __forceinline__ float bf2f(unsigned short h){
    union { unsigned int u; float f; } v; v.u = ((unsigned int)h) << 16;
    return v.f;
}

// LDS tile: 64B rows (32 bf16), 16B slots, XOR swizzle spreads rows over slots.
// addr' bijective: bits7,8 fixed; b6'=b6^b8; b5'=b5^b7; b4'=b4^b6(recoverable).
__device__ __forceinline__ int swz(int row, int kb){
    return (row*64 + kb) ^ ((row & 7) << 4);
}

// ---------- weight packing (transposed [n][col][k], bf16) ----------
// Gates: packed col pc: cb=pc>>7, r=pc&127, g=r>>5 (0:r,1:z,2:gx,3:gh), ol=r&31, o=cb*32+ol
__global__ void pack_gates(const float* __restrict__ Wh2h, const float* __restrict__ Wx2h,
                           unsigned short* __restrict__ Wg)
{
    int idx = blockIdx.x*256 + threadIdx.x;
    const int total = 8*1024*288;
    if (idx >= total) return;
    int k  = idx % 288;
    int pc = (idx / 288) % 1024;
    int n  = idx / (288*1024);
    int cb = pc >> 7, r = pc & 127;
    int g = r >> 5, ol = r & 31;
    int o = cb*32 + ol;
    float v = 0.f;
    if (g == 0)      v = (k < 256) ? Wh2h[((size_t)n*256 + k)*768 + o]
                                   : Wx2h[((size_t)n*32 + (k-256))*768 + o];
    else if (g == 1) v = (k < 256) ? Wh2h[((size_t)n*256 + k)*768 + 256 + o]
                                   : Wx2h[((size_t)n*32 + (k-256))*768 + 256 + o];
    else if (g == 2) v = (k >= 256) ? Wx2h[((size_t)n*32 + (k-256))*768 + 512 + o] : 0.f;
    else             v = (k < 256) ? Wh2h[((size_t)n*256 + k)*768 + 512 + o] : 0.f;
    Wg[idx] = f2bf(v);
}

__global__ void pack_qkv(const float* __restrict__ Wq_, const float* __restrict__ Wk_,
                         const float* __restrict__ Wv_, unsigned short* __restrict__ Wqkv)
{
    int idx = blockIdx.x*256 + threadIdx.x;
    const int total = 8*1152*256;
    if (idx >= total) return;
    int k = idx % 256;
    int c = (idx / 256) % 1152;
    int n = idx / (256*1152);
    float v = 0.f;
    if (c < 32)        v = Wq_[((size_t)n*256+k)*32 + c];
    else if (c < 64)   v = Wk_[((size_t)n*256+k)*32 + (c-32)];
    else if (c < 1088) v = Wv_[((size_t)n*256+k)*1024 + (c-64)];
    Wqkv[idx] = f2bf(v);
}

__global__ void pack_out(const float* __restrict__ Wout, unsigned short* __restrict__ Wt)
{
    int idx = blockIdx.x*256 + threadIdx.x;
    const int total = 8*256*1024;
    if (idx >= total) return;
    int k = idx % 1024;
    int c = (idx / 1024) % 256;
    int n = idx / (1024*256);
    Wt[idx] = f2bf(Wout[((size_t)n*1024 + k)*256 + c]);
}

// ---------- stage A (full B): input attention, mask, inputs (bf16) ----------
__global__ __launch_bounds__(64) void stage_a(
    const float* __restrict__ x1, const float* __restrict__ x2,
    const float* __restrict__ hs,
    const float* __restrict__ Wkey, const float* __restrict__ bkey,
    const float* __restrict__ Wval, const float* __restrict__ bval,
    const float* __restrict__ Wq,
    unsigned short* __restrict__ inputs, float* __restrict__ maskf)
{
    int gb = blockIdx.x;
    int l  = threadIdx.x;

    __shared__ float vv[3][32];
    __shared__ float xk[3][16];
    __shared__ float qL[8][16];
    __shared__ float sc[8][3];
    __shared__ float pr[8][3];
    __shared__ float mk[8];

    const float* x1r = x1 + (size_t)gb*HH;
    const float* x2r = x2 + (size_t)gb*HH;

    {
        int s = l >> 5, d = l & 31;
        const float* xr = s ? x2r : x1r;
        float acc = bval[d];
        for (int h = 0; h < HH; ++h) acc += xr[h]*Wval[h*32 + d];
        vv[s][d] = acc;
        if (l < 32) vv[2][l] = bval[l];
    }
    if (l < 32) {
        int s = l >> 4, k = l & 15;
        const float* xr = s ? x2r : x1r;
        float acc = bkey[k];
        for (int h = 0; h < HH; ++h) acc += xr[h]*Wkey[h*16 + k];
        xk[s][k] = acc;
    } else if (l < 48) {
        xk[2][l-32] = bkey[l-32];
    }
    for (int it = 0; it < 2; ++it) {
        int idx = l + 64*it;
        int n = idx >> 4, k = idx & 15;
        const float* hr = hs + ((size_t)gb*NU + n)*HH;
        float acc = 0.f;
        for (int h = 0; h < HH; ++h) acc += hr[h]*Wq[((size_t)n*HH + h)*16 + k];
        qL[n][k] = acc;
    }
    __syncthreads();

    if (l < 24) {
        int n = l/3, s = l%3;
        float acc = 0.f;
        for (int k = 0; k < 16; ++k) acc += qL[n][k]*xk[s][k];
        sc[n][s] = acc * 0.25f;
    }
    __syncthreads();

    if (l < 8) {
        float a0 = sc[l][0], a1 = sc[l][1], a2 = sc[l][2];
        float m  = fmaxf(a0, fmaxf(a1, a2));
        float e0 = expf(a0-m), e1 = expf(a1-m), e2 = expf(a2-m);
        float inv = 1.f/(e0+e1+e2);
        pr[l][0] = e0*inv; pr[l][1] = e1*inv; pr[l][2] = e2*inv;
    }
    __syncthreads();

    if (l < 8) {
        float sn = sc[l][2];
        int rank = 0;
        for (int m = 0; m < 8; ++m) {
            float sm = sc[m][2];
            if (sm > sn || (sm == sn && m < l)) rank++;
        }
        float mv = (rank < 4) ? 0.f : 1.f;
        mk[l] = mv;
        maskf[(size_t)gb*8 + l] = mv;
    }
    __syncthreads();

    for (int it = 0; it < 4; ++it) {
        int idx = l + 64*it;
        int n = idx >> 5, d = idx & 31;
        float v = mk[n]*(pr[n][0]*vv[0][d] + pr[n][1]*vv[1][d] + pr[n][2]*vv[2][d]);
        inputs[((size_t)n*B_TOT + gb)*32 + d] = f2bf(v);
    }
}

// ---------- per-batch 4-head attention over 8 units; ctx written in-place over v2 ----------
__global__ __launch_bounds__(64) void attn_kernel(
    unsigned short* __restrict__ QKV, const float* __restrict__ maskf, int Bc, int c0)
{
    int b = blockIdx.x;
    int gb = c0 + b;
    int l = threadIdx.x;
    __shared__ float qk[8][64];
    __shared__ float P[4][8][8];

    for (int it = 0; it < 8; ++it) {
        int idx = l + 64*it;
        int n = idx >> 6, c = idx & 63;
        qk[n][c] = bf2f(QKV[((size_t)n*Bc + b)*1152 + c]);
    }
    __syncthreads();

    for (int it = 0; it < 4; ++it) {
        int idx = l + 64*it;
        int h = idx >> 6, n = (idx >> 3) & 7, m = idx & 7;
        float s = 0.f;
        for (int dk = 0; dk < 8; ++dk) s += qk[n][h*8 + dk]*qk[m][32 + h*8 + dk];
        P[h][n][m] = s * 0.35355339059327373f;
    }
    __syncthreads();

    if (l < 32) {
        int h = l >> 3, n = l & 7;
        float mx = -1e30f;
        for (int m = 0; m < 8; ++m) mx = fmaxf(mx, P[h][n][m]);
        float e[8], sum = 0.f;
        for (int m = 0; m < 8; ++m) { e[m] = expf(P[h][n][m]-mx); sum += e[m]; }
        float scl = maskf[(size_t)gb*8 + n] / sum;
        for (int m = 0; m < 8; ++m) P[h][n][m] = e[m]*scl;
    }
    __syncthreads();

    // each thread owns col-chunk colb exclusively: reads v2[m][colb] all m, then writes ctx[n][colb] all n
    #pragma unroll
    for (int it = 0; it < 2; ++it) {
        int colb = (l + 64*it)*8;
        int h = colb >> 8;
        float acc[8][8];
        #pragma unroll
        for (int n = 0; n < 8; ++n)
            #pragma unroll
            for (int c = 0; c < 8; ++c) acc[n][c] = 0.f;
        for (int m = 0; m < 8; ++m) {
            bf16x8 v8 = *(const bf16x8*)&QKV[((size_t)m*Bc + b)*1152 + 64 + colb];
            float vf[8];
            #pragma unroll
            for (int c = 0; c < 8; ++c) vf[c] = bf2f((unsigned short)v8[c]);
            #pragma unroll
            for (int n = 0; n < 8; ++n) {
                float p = P[h][n][m];
                #pragma unroll
                for (int c = 0; c < 8; ++c) acc[n][c] += p*vf[c];
            }
        }
        #pragma unroll
        for (int n = 0; n < 8; ++n) {
            bf16x8 o;
            #pragma unroll
            for (int c = 0; c < 8; ++c) o[c] = (short)f2bf(acc[n][c]);
            *(bf16x8*)&QKV[((size_t)n*Bc + b)*1152 + 64 + colb] = o;
        }
    }
}

// ---------- MFMA GEMM, double-buffered + prefetch, n->XCD mapping ----------
// MODE 0: gates+GRU fused. A: hs fp32 (k<256) + inputs bf16. Writes hsnb.
// MODE 1: qkv. A = hsnb. Writes QKV bf16 (M=1152).
// MODE 2: out. A = QKV+64 (ctx). Epilogue: + hsnb, mask blend, write d_out fp32.
template<int MODE, int TN>
__global__ __launch_bounds__(256) void gemm_mfma(
    const float* __restrict__ hs_glob,
    const unsigned short* __restrict__ inputs,
    const unsigned short* __restrict__ Asrc,
    const unsigned short* __restrict__ Wp,
    unsigned short* __restrict__ hsnb,
    unsigned short* __restrict__ QKV,
    const float* __restrict__ maskf,
    float* __restrict__ outp,
    int Bc, int c0)
{
    constexpr int KW   = (MODE==0) ? 288 : (MODE==1 ? 256 : 1024);
    constexpr int M    = (MODE==0) ? 1024 : (MODE==1 ? 1152 : 256);
    constexpr int NJ   = TN/16;
    constexpr int NT   = KW/32;
    constexpr int ASTR = (MODE==2) ? 1152 : 256;

    int bid = blockIdx.x;
    int n   = bid & 7;                 // unit == XCD: weights stay in one L2
    int loc = bid >> 3;
    int RB  = Bc >> 7;
    int row0 = (loc % RB) * 128;       // rows fastest: W panel reused back-to-back
    int col0 = (loc / RB) * TN;

    __shared__ unsigned short As[2][128*32];
    __shared__ unsigned short Ws[2][TN*32];

    int t = threadIdx.x;
    int l = t & 63, w = t >> 6;
    int lr = l & 15, lk = l >> 4;

    int arow = t >> 1, aseg = t & 1;   // A staging: 128 rows x 2 k-halves (32B/thread)
    int wrow, wkb;
    if (TN == 128) { wrow = t >> 1; wkb = (t & 1) * 32; }
    else           { wrow = t >> 2; wkb = (t & 3) * 16; }

    f32x4 acc[2][NJ];
    #pragma unroll
    for (int i = 0; i < 2; ++i)
        #pragma unroll
        for (int j = 0; j < NJ; ++j)
            acc[i][j] = (f32x4){0.f,0.f,0.f,0.f};

    bf16x8 au0, au1, wu0, wu1;

    auto loadA = [&](int k0, bf16x8 &u0, bf16x8 &u1) {
        if (MODE == 0) {
            if (k0 < 256) {
                const float4* s4 = (const float4*)(hs_glob +
                    (((size_t)(c0 + row0 + arow))*NU + n)*HH + k0 + aseg*16);
                float4 f0 = s4[0], f1 = s4[1], f2 = s4[2], f3 = s4[3];
                u0[0]=(short)f2bf(f0.x); u0[1]=(short)f2bf(f0.y); u0[2]=(short)f2bf(f0.z); u0[3]=(short)f2bf(f0.w);
                u0[4]=(short)f2bf(f1.x); u0[5]=(short)f2bf(f1.y); u0[6]=(short)f2bf(f1.z); u0[7]=(short)f2bf(f1.w);
                u1[0]=(short)f2bf(f2.x); u1[1]=(short)f2bf(f2.y); u1[2]=(short)f2bf(f2.z); u1[3]=(short)f2bf(f2.w);
                u1[4]=(short)f2bf(f3.x); u1[5]=(short)f2bf(f3.y); u1[6]=(short)f2bf(f3.z); u1[7]=(short)f2bf(f3.w);
            } else {
                const bf16x8* s = (const bf16x8*)(inputs +
                    ((size_t)n*B_TOT + c0 + row0 + arow)*32 + aseg*16);
                u0 = s[0]; u1 = s[1];
            }
        } else {
            const unsigned short* s = Asrc + ((size_t)n*Bc + row0 + arow)*ASTR + k0 + aseg*16;
            u0 = ((const bf16x8*)s)[0];
            u1 = ((const bf16x8*)s)[1];
        }
    };
    auto loadW = [&](int k0, bf16x8 &u0, bf16x8 &u1) {
        const unsigned short* s = Wp + ((size_t)n*M + col0 + wrow)*(size_t)KW + k0 + (wkb >> 1);
        u0 = ((const bf16x8*)s)[0];
        if (TN == 128) u1 = ((const bf16x8*)s)[1];
    };

    loadA(0, au0, au1);
    loadW(0, wu0, wu1);

    for (int tt = 0; tt < NT; ++tt) {
        char* A_ = (char*)&As[tt & 1][0];
        char* W_ = (char*)&Ws[tt & 1][0];
        *(bf16x8*)(A_ + swz(arow, aseg*32))      = au0;
        *(bf16x8*)(A_ + swz(arow, aseg*32 + 16)) = au1;
        *(bf16x8*)(W_ + swz(wrow, wkb))          = wu0;
        if (TN == 128) *(bf16x8*)(W_ + swz(wrow, wkb + 16)) = wu1;
        __syncthreads();
        if (tt + 1 < NT) {               // prefetch next K-tile under the MFMAs
            loadA((tt+1)*32, au0, au1);
            loadW((tt+1)*32, wu0, wu1);
        }
        bf16x8 a0 = *(bf16x8*)(A_ + swz(w*32 + lr,      lk*16));
        bf16x8 a1 = *(bf16x8*)(A_ + swz(w*32 + 16 + lr, lk*16));
        bf16x8 bq[NJ];
        #pragma unroll
        for (int j = 0; j < NJ; ++j)
            bq[j] = *(bf16x8*)(W_ + swz(j*16 + lr, lk*16));
        #pragma unroll
        for (int j = 0; j < NJ; ++j)
            acc[0][j] = __builtin_amdgcn_mfma_f32_16x16x32_bf16(a0, bq[j], acc[0][j], 0, 0, 0);
        #pragma unroll
        for (int j = 0; j < NJ; ++j)
            acc[1][j] = __builtin_amdgcn_mfma_f32_16x16x32_bf16(a1, bq[j], acc[1][j], 0, 0, 0);
        // no trailing barrier: next iter's barrier (other buffer) protects reuse
    }

    if constexpr (MODE == 0) {
        // block cols = o-range [col0>>2, +32) x 4 gate groups; GRU in-register
        #pragma unroll
        for (int i = 0; i < 2; ++i) {
            int rbase = row0 + w*32 + i*16 + lk*4;
            #pragma unroll
            for (int half = 0; half < 2; ++half) {
                int o = (col0 >> 2) + half*16 + lr;
                #pragma unroll
                for (int reg = 0; reg < 4; ++reg) {
                    int r = rbase + reg;
                    float rs = acc[i][0+half][reg];
                    float zs = acc[i][2+half][reg];
                    float gx = acc[i][4+half][reg];
                    float gh = acc[i][6+half][reg];
                    float hold = hs_glob[(((size_t)(c0 + r))*NU + n)*HH + o];
                    float rr = sigm(rs), z = sigm(zs);
                    float nn = tanhf(gx + rr*gh);
                    float h  = nn + z*(hold - nn);
                    hsnb[((size_t)n*Bc + r)*256 + o] = f2bf(h);
                }
            }
        }
    } else if constexpr (MODE == 1) {
        #pragma unroll
        for (int i = 0; i < 2; ++i) {
            #pragma unroll
            for (int j = 0; j < NJ; ++j) {
                int c = col0 + j*16 + lr;
                #pragma unroll
                for (int reg = 0; reg < 4; ++reg) {
                    int r = row0 + w*32 + i*16 + lk*4 + reg;
                    QKV[((size_t)n*Bc + r)*1152 + c] = f2bf(acc[i][j][reg]);
                }
            }
        }
    } else {
        #pragma unroll
        for (int i = 0; i < 2; ++i) {
            #pragma unroll
            for (int reg = 0; reg < 4; ++reg) {
                int r = row0 + w*32 + i*16 + lk*4 + reg;
                float mkv = maskf[(size_t)(c0 + r)*8 + n];
                #pragma unroll
                for (int j = 0; j < NJ; ++j) {
                    int c = col0 + j*16 + lr;
                    size_t gi = (((size_t)(c0 + r))*NU + n)*HH + c;
                    float v;
                    if (mkv != 0.f) v = acc[i][j][reg] + bf2f(hsnb[((size_t)n*Bc + r)*256 + c]);
                    else            v = hs_glob[gi];
                    outp[gi] = v;
                }
            }
        }
    }
}

extern "C" void kernel_launch(void* const* d_in, const int* in_sizes, int n_in,
                              void* d_out, int out_size, void* d_ws, size_t ws_size,
                              hipStream_t stream)
{
    const float* x1   = (const float*)d_in[0];
    const float* x2   = (const float*)d_in[1];
    const float* hs   = (const float*)d_in[2];
    const float* Wkey = (const float*)d_in[3];
    const float* bkey = (const float*)d_in[4];
    const float* Wval = (const float*)d_in[5];
    const float* bval = (const float*)d_in[6];
    const float* Wq   = (const float*)d_in[7];
    const float* Wq_  = (const float*)d_in[8];
    const float* Wk_  = (const float*)d_in[9];
    const float* Wv_  = (const float*)d_in[10];
    const float* Wout = (const float*)d_in[11];
    const float* Wx2h = (const float*)d_in[12];
    const float* Wh2h = (const float*)d_in[13];
    float* out = (float*)d_out;

    char* ws = (char*)d_ws;
    size_t off = 0;
    auto alloc = [&](size_t bytes) -> void* {
        void* p = (void*)(ws + off);
        off = (off + bytes + 255) & ~(size_t)255;
        return p;
    };
    unsigned short* Wg     = (unsigned short*)alloc((size_t)8*1024*288*2);
    unsigned short* Wqkv   = (unsigned short*)alloc((size_t)8*1152*256*2);
    unsigned short* WoutT  = (unsigned short*)alloc((size_t)8*256*1024*2);
    unsigned short* inputs = (unsigned short*)alloc((size_t)8*B_TOT*32*2);
    float*          maskf  = (float*)         alloc((size_t)B_TOT*8*4);
    size_t persist = off;

    // per-batch chunk bytes: hsnb 4096 + QKV 18432
    const size_t perB = 8*256*2 + 8*1152*2;
    int Bc = B_TOT;
    while (Bc > 128 && persist + (size_t)Bc*perB + 65536 > ws_size) Bc >>= 1;
    unsigned short* hsnb = (unsigned short*)alloc((size_t)8*Bc*256*2);
    unsigned short* QKV  = (unsigned short*)alloc((size_t)8*Bc*1152*2);

    pack_gates<<<(8*1024*288 + 255)/256, 256, 0, stream>>>(Wh2h, Wx2h, Wg);
    pack_qkv  <<<(8*1152*256 + 255)/256, 256, 0, stream>>>(Wq_, Wk_, Wv_, Wqkv);
    pack_out  <<<(8*256*1024 + 255)/256, 256, 0, stream>>>(Wout, WoutT);
    stage_a<<<B_TOT, 64, 0, stream>>>(x1, x2, hs, Wkey, bkey, Wval, bval, Wq,
                                      inputs, maskf);

    for (int c0 = 0; c0 < B_TOT; c0 += Bc) {
        int RB = Bc / 128;
        gemm_mfma<0,128><<<dim3(RB*8*8), 256, 0, stream>>>(
            hs, inputs, nullptr, Wg, hsnb, nullptr, nullptr, nullptr, Bc, c0);
        gemm_mfma<1,128><<<dim3(RB*9*8), 256, 0, stream>>>(
            hs, nullptr, hsnb, Wqkv, nullptr, QKV, nullptr, nullptr, Bc, c0);
        attn_kernel<<<Bc, 64, 0, stream>>>(QKV, maskf, Bc, c0);
        gemm_mfma<2,64><<<dim3(RB*4*8), 256, 0, stream>>>(
            hs, nullptr, QKV + 64, WoutT, hsnb, nullptr, maskf, out, Bc, c0);
    }
}

// Round 4
// 469.122 us; speedup vs baseline: 3.9243x; 1.2062x over previous
//
#include <hip/hip_runtime.h>
#include <math.h>

// BRIMCell forward — bf16 MFMA everywhere GEMM-shaped; fused GRU; latency-bound
// stages rebuilt as small MFMA GEMMs + tiny pointwise kernels.
// B=8192, N=8, H=D=256.

#define B_TOT 8192
#define NU 8
#define HH 256

typedef __attribute__((ext_vector_type(8))) short bf16x8;
typedef __attribute__((ext_vector_type(4))) float f32x4;

__device__ __forceinline__ float sigm(float x){ return 1.0f/(1.0f+expf(-x)); }

__device__ __forceinline__ unsigned short f2bf(float f){
    union { float f; unsigned int u; } v; v.f = f;
    unsigned int r = v.u + 0x7fffu + ((v.u >> 16) & 1u);
    return (unsigned short)(r >> 16);
}
__device__ __forceinline__ float bf2f(unsigned short h){
    union { unsigned int u; float f; } v; v.u = ((unsigned int)h) << 16;
    return v.f;
}

// LDS tile: 64B rows (32 bf16), 16B slots, XOR swizzle (bijective per 512B group).
__device__ __forceinline__ int swz(int row, int kb){
    return (row*64 + kb) ^ ((row & 7) << 4);
}

// ---------- weight packing (transposed [n][col][k], bf16) ----------
__global__ void pack_gates(const float* __restrict__ Wh2h, const float* __restrict__ Wx2h,
                           unsigned short* __restrict__ Wg)
{
    int idx = blockIdx.x*256 + threadIdx.x;
    const int total = 8*1024*288;
    if (idx >= total) return;
    int k  = idx % 288;
    int pc = (idx / 288) % 1024;
    int n  = idx / (288*1024);
    int cb = pc >> 7, r = pc & 127;
    int g = r >> 5, ol = r & 31;
    int o = cb*32 + ol;
    float v = 0.f;
    if (g == 0)      v = (k < 256) ? Wh2h[((size_t)n*256 + k)*768 + o]
                                   : Wx2h[((size_t)n*32 + (k-256))*768 + o];
    else if (g == 1) v = (k < 256) ? Wh2h[((size_t)n*256 + k)*768 + 256 + o]
                                   : Wx2h[((size_t)n*32 + (k-256))*768 + 256 + o];
    else if (g == 2) v = (k >= 256) ? Wx2h[((size_t)n*32 + (k-256))*768 + 512 + o] : 0.f;
    else             v = (k < 256) ? Wh2h[((size_t)n*256 + k)*768 + 512 + o] : 0.f;
    Wg[idx] = f2bf(v);
}

__global__ void pack_qkv(const float* __restrict__ Wq_, const float* __restrict__ Wk_,
                         const float* __restrict__ Wv_, unsigned short* __restrict__ Wqkv)
{
    int idx = blockIdx.x*256 + threadIdx.x;
    const int total = 8*1152*256;
    if (idx >= total) return;
    int k = idx % 256;
    int c = (idx / 256) % 1152;
    int n = idx / (256*1152);
    float v = 0.f;
    if (c < 32)        v = Wq_[((size_t)n*256+k)*32 + c];
    else if (c < 64)   v = Wk_[((size_t)n*256+k)*32 + (c-32)];
    else if (c < 1088) v = Wv_[((size_t)n*256+k)*1024 + (c-64)];
    Wqkv[idx] = f2bf(v);
}

__global__ void pack_out(const float* __restrict__ Wout, unsigned short* __restrict__ Wt)
{
    int idx = blockIdx.x*256 + threadIdx.x;
    const int total = 8*256*1024;
    if (idx >= total) return;
    int k = idx % 1024;
    int c = (idx / 1024) % 256;
    int n = idx / (1024*256);
    Wt[idx] = f2bf(Wout[((size_t)n*1024 + k)*256 + c]);
}

__global__ void pack_kvw(const float* __restrict__ Wkey, const float* __restrict__ Wval,
                         unsigned short* __restrict__ Wkv)
{
    int idx = blockIdx.x*256 + threadIdx.x;
    if (idx >= 48*256) return;
    int k = idx & 255, c = idx >> 8;
    float v = (c < 16) ? Wkey[k*16 + c] : Wval[k*32 + (c-16)];
    Wkv[(size_t)c*256 + k] = f2bf(v);
}

__global__ void pack_qlw(const float* __restrict__ Wq, unsigned short* __restrict__ Wqt)
{
    int idx = blockIdx.x*256 + threadIdx.x;
    if (idx >= 8*16*256) return;
    int k = idx & 255, c = (idx >> 8) & 15, n = idx >> 12;
    Wqt[((size_t)n*16 + c)*256 + k] = f2bf(Wq[((size_t)n*256 + k)*16 + c]);
}

// ---------- small MFMA GEMM for stage-A precursors ----------
// SRC 0: KV[16384][48] = [x1;x2](fp32) @ Wkv^T, M=48
// SRC 1: qL[n][8192][16] = hs_unit(fp32) @ Wqt[n]^T, M=16
template<int SRC>
__global__ __launch_bounds__(256) void small_gemm(
    const float* __restrict__ A0, const float* __restrict__ A1,
    const unsigned short* __restrict__ Wp, float* __restrict__ C)
{
    constexpr int M  = (SRC == 0) ? 48 : 16;
    constexpr int NJ = M/16;
    int row0 = blockIdx.x * 128;
    int n = (SRC == 1) ? blockIdx.y : 0;
    const unsigned short* W = Wp + (size_t)n*M*256;

    __shared__ unsigned short As[2][128*32];
    __shared__ unsigned short Ws[2][M*32];

    int t = threadIdx.x, l = t & 63, w = t >> 6;
    int lr = l & 15, lk = l >> 4;
    int arow = t >> 1, aseg = t & 1;

    f32x4 acc[2][NJ];
    #pragma unroll
    for (int i = 0; i < 2; ++i)
        #pragma unroll
        for (int j = 0; j < NJ; ++j)
            acc[i][j] = (f32x4){0.f,0.f,0.f,0.f};

    bf16x8 au0, au1, wu0, wu1;
    auto loadA = [&](int k0, bf16x8 &u0, bf16x8 &u1) {
        const float* src;
        if (SRC == 0) {
            int gr = row0 + arow;
            src = (gr < B_TOT ? A0 + (size_t)gr*HH : A1 + (size_t)(gr - B_TOT)*HH) + k0 + aseg*16;
        } else {
            src = A0 + (((size_t)(row0 + arow))*NU + n)*HH + k0 + aseg*16;
        }
        const float4* s4 = (const float4*)src;
        float4 f0 = s4[0], f1 = s4[1], f2 = s4[2], f3 = s4[3];
        u0[0]=(short)f2bf(f0.x); u0[1]=(short)f2bf(f0.y); u0[2]=(short)f2bf(f0.z); u0[3]=(short)f2bf(f0.w);
        u0[4]=(short)f2bf(f1.x); u0[5]=(short)f2bf(f1.y); u0[6]=(short)f2bf(f1.z); u0[7]=(short)f2bf(f1.w);
        u1[0]=(short)f2bf(f2.x); u1[1]=(short)f2bf(f2.y); u1[2]=(short)f2bf(f2.z); u1[3]=(short)f2bf(f2.w);
        u1[4]=(short)f2bf(f3.x); u1[5]=(short)f2bf(f3.y); u1[6]=(short)f2bf(f3.z); u1[7]=(short)f2bf(f3.w);
    };
    auto loadW = [&](int k0, bf16x8 &u0, bf16x8 &u1) {
        if (t < M*2) {
            const unsigned short* s = W + (size_t)(t >> 1)*256 + k0 + (t & 1)*16;
            u0 = ((const bf16x8*)s)[0];
            u1 = ((const bf16x8*)s)[1];
        }
    };

    loadA(0, au0, au1);
    loadW(0, wu0, wu1);

    for (int tt = 0; tt < 8; ++tt) {
        char* A_ = (char*)&As[tt & 1][0];
        char* W_ = (char*)&Ws[tt & 1][0];
        *(bf16x8*)(A_ + swz(arow, aseg*32))      = au0;
        *(bf16x8*)(A_ + swz(arow, aseg*32 + 16)) = au1;
        if (t < M*2) {
            *(bf16x8*)(W_ + swz(t >> 1, (t & 1)*32))      = wu0;
            *(bf16x8*)(W_ + swz(t >> 1, (t & 1)*32 + 16)) = wu1;
        }
        __syncthreads();
        if (tt + 1 < 8) {
            loadA((tt+1)*32, au0, au1);
            loadW((tt+1)*32, wu0, wu1);
        }
        bf16x8 a0 = *(bf16x8*)(A_ + swz(w*32 + lr,      lk*16));
        bf16x8 a1 = *(bf16x8*)(A_ + swz(w*32 + 16 + lr, lk*16));
        bf16x8 bq[NJ];
        #pragma unroll
        for (int j = 0; j < NJ; ++j)
            bq[j] = *(bf16x8*)(W_ + swz(j*16 + lr, lk*16));
        #pragma unroll
        for (int j = 0; j < NJ; ++j) {
            acc[0][j] = __builtin_amdgcn_mfma_f32_16x16x32_bf16(a0, bq[j], acc[0][j], 0, 0, 0);
            acc[1][j] = __builtin_amdgcn_mfma_f32_16x16x32_bf16(a1, bq[j], acc[1][j], 0, 0, 0);
        }
    }

    float* Cb = (SRC == 0) ? C : C + (size_t)n*B_TOT*16;
    #pragma unroll
    for (int i = 0; i < 2; ++i)
        #pragma unroll
        for (int j = 0; j < NJ; ++j)
            #pragma unroll
            for (int reg = 0; reg < 4; ++reg) {
                int r = row0 + w*32 + i*16 + lk*4 + reg;
                Cb[(size_t)r*M + j*16 + lr] = acc[i][j][reg];
            }
}

// ---------- scores -> softmax -> mask -> inputs (1 thread per (batch,unit)) ----------
__global__ __launch_bounds__(256) void score_mask_inputs(
    const float* __restrict__ KV,   // [16384][48]
    const float* __restrict__ qL,   // [8][8192][16]
    const float* __restrict__ bkey, const float* __restrict__ bval,
    unsigned short* __restrict__ inputs, float* __restrict__ maskf)
{
    int t  = threadIdx.x;
    int gb = blockIdx.x*32 + (t >> 3);
    int n  = t & 7, l = t & 63;

    float q[16];
    const float* qp = qL + ((size_t)n*B_TOT + gb)*16;
    #pragma unroll
    for (int i = 0; i < 4; ++i) *(float4*)&q[i*4] = ((const float4*)qp)[i];

    const float* kv0 = KV + (size_t)gb*48;
    const float* kv1 = KV + (size_t)(B_TOT + gb)*48;

    float s0 = 0.f, s1 = 0.f, sn = 0.f;
    #pragma unroll
    for (int k = 0; k < 16; ++k) {
        float bk = bkey[k];
        s0 += q[k]*(kv0[k] + bk);
        s1 += q[k]*(kv1[k] + bk);
        sn += q[k]*bk;
    }
    s0 *= 0.25f; s1 *= 0.25f; sn *= 0.25f;

    float mx = fmaxf(s0, fmaxf(s1, sn));
    float e0 = expf(s0-mx), e1 = expf(s1-mx), en = expf(sn-mx);
    float inv = 1.f/(e0+e1+en);
    float p0 = e0*inv, p1 = e1*inv, pn = en*inv;

    int rank = 0;
    #pragma unroll
    for (int m = 0; m < 8; ++m) {
        float sm = __shfl(sn, (l & ~7) + m, 64);
        if (sm > sn || (sm == sn && m < n)) rank++;
    }
    float mk = (rank < 4) ? 0.f : 1.f;
    maskf[(size_t)gb*8 + n] = mk;

    unsigned short* op = inputs + ((size_t)n*B_TOT + gb)*32;
    #pragma unroll
    for (int db = 0; db < 4; ++db) {
        bf16x8 o;
        #pragma unroll
        for (int e = 0; e < 8; ++e) {
            int d = db*8 + e;
            float bv = bval[d];
            float v = mk*(p0*(kv0[16+d]+bv) + p1*(kv1[16+d]+bv) + pn*bv);
            o[e] = (short)f2bf(v);
        }
        *(bf16x8*)&op[db*8] = o;
    }
}

// ---------- per-batch 4-head attention; 4 batches/block; ctx in-place over v2 ----------
__global__ __launch_bounds__(256) void attn_kernel(
    unsigned short* __restrict__ QKV, const float* __restrict__ maskf, int Bc, int c0)
{
    int wid = threadIdx.x >> 6;
    int l   = threadIdx.x & 63;
    int b   = blockIdx.x*4 + wid;
    int gb  = c0 + b;

    __shared__ float qk[4][8][64];
    __shared__ float P[4][4][8][8];

    for (int it = 0; it < 8; ++it) {
        int idx = l + 64*it;
        int n = idx >> 6, c = idx & 63;
        qk[wid][n][c] = bf2f(QKV[((size_t)n*Bc + b)*1152 + c]);
    }
    __syncthreads();

    for (int it = 0; it < 4; ++it) {
        int idx = l + 64*it;
        int h = idx >> 6, n = (idx >> 3) & 7, m = idx & 7;
        float s = 0.f;
        #pragma unroll
        for (int dk = 0; dk < 8; ++dk) s += qk[wid][n][h*8 + dk]*qk[wid][m][32 + h*8 + dk];
        P[wid][h][n][m] = s * 0.35355339059327373f;
    }
    __syncthreads();

    if (l < 32) {
        int h = l >> 3, n = l & 7;
        float mx = -1e30f;
        for (int m = 0; m < 8; ++m) mx = fmaxf(mx, P[wid][h][n][m]);
        float e[8], sum = 0.f;
        for (int m = 0; m < 8; ++m) { e[m] = expf(P[wid][h][n][m]-mx); sum += e[m]; }
        float scl = maskf[(size_t)gb*8 + n] / sum;
        for (int m = 0; m < 8; ++m) P[wid][h][n][m] = e[m]*scl;
    }
    __syncthreads();

    #pragma unroll
    for (int it = 0; it < 2; ++it) {
        int colb = (l + 64*it)*8;
        int h = colb >> 8;
        float acc[8][8];
        #pragma unroll
        for (int n = 0; n < 8; ++n)
            #pragma unroll
            for (int c = 0; c < 8; ++c) acc[n][c] = 0.f;
        for (int m = 0; m < 8; ++m) {
            bf16x8 v8 = *(const bf16x8*)&QKV[((size_t)m*Bc + b)*1152 + 64 + colb];
            float vf[8];
            #pragma unroll
            for (int c = 0; c < 8; ++c) vf[c] = bf2f((unsigned short)v8[c]);
            #pragma unroll
            for (int n = 0; n < 8; ++n) {
                float p = P[wid][h][n][m];
                #pragma unroll
                for (int c = 0; c < 8; ++c) acc[n][c] += p*vf[c];
            }
        }
        #pragma unroll
        for (int n = 0; n < 8; ++n) {
            bf16x8 o;
            #pragma unroll
            for (int c = 0; c < 8; ++c) o[c] = (short)f2bf(acc[n][c]);
            *(bf16x8*)&QKV[((size_t)n*Bc + b)*1152 + 64 + colb] = o;
        }
    }
}

// ---------- MFMA GEMM, double-buffered + prefetch, n->XCD mapping ----------
// MODE 0: gates+GRU fused. MODE 1: qkv. MODE 2: out + epilogue.
template<int MODE, int TN>
__global__ __launch_bounds__(256) void gemm_mfma(
    const float* __restrict__ hs_glob,
    const unsigned short* __restrict__ inputs,
    const unsigned short* __restrict__ Asrc,
    const unsigned short* __restrict__ Wp,
    unsigned short* __restrict__ hsnb,
    unsigned short* __restrict__ QKV,
    const float* __restrict__ maskf,
    float* __restrict__ outp,
    int Bc, int c0)
{
    constexpr int KW   = (MODE==0) ? 288 : (MODE==1 ? 256 : 1024);
    constexpr int M    = (MODE==0) ? 1024 : (MODE==1 ? 1152 : 256);
    constexpr int NJ   = TN/16;
    constexpr int NT   = KW/32;
    constexpr int ASTR = (MODE==2) ? 1152 : 256;

    int bid = blockIdx.x;
    int n   = bid & 7;
    int loc = bid >> 3;
    int RB  = Bc >> 7;
    int row0 = (loc % RB) * 128;
    int col0 = (loc / RB) * TN;

    __shared__ unsigned short As[2][128*32];
    __shared__ unsigned short Ws[2][TN*32];

    int t = threadIdx.x;
    int l = t & 63, w = t >> 6;
    int lr = l & 15, lk = l >> 4;

    int arow = t >> 1, aseg = t & 1;
    int wrow, wkb;
    if (TN == 128) { wrow = t >> 1; wkb = (t & 1) * 32; }
    else           { wrow = t >> 2; wkb = (t & 3) * 16; }

    f32x4 acc[2][NJ];
    #pragma unroll
    for (int i = 0; i < 2; ++i)
        #pragma unroll
        for (int j = 0; j < NJ; ++j)
            acc[i][j] = (f32x4){0.f,0.f,0.f,0.f};

    bf16x8 au0, au1, wu0, wu1;

    auto loadA = [&](int k0, bf16x8 &u0, bf16x8 &u1) {
        if (MODE == 0) {
            if (k0 < 256) {
                const float4* s4 = (const float4*)(hs_glob +
                    (((size_t)(c0 + row0 + arow))*NU + n)*HH + k0 + aseg*16);
                float4 f0 = s4[0], f1 = s4[1], f2 = s4[2], f3 = s4[3];
                u0[0]=(short)f2bf(f0.x); u0[1]=(short)f2bf(f0.y); u0[2]=(short)f2bf(f0.z); u0[3]=(short)f2bf(f0.w);
                u0[4]=(short)f2bf(f1.x); u0[5]=(short)f2bf(f1.y); u0[6]=(short)f2bf(f1.z); u0[7]=(short)f2bf(f1.w);
                u1[0]=(short)f2bf(f2.x); u1[1]=(short)f2bf(f2.y); u1[2]=(short)f2bf(f2.z); u1[3]=(short)f2bf(f2.w);
                u1[4]=(short)f2bf(f3.x); u1[5]=(short)f2bf(f3.y); u1[6]=(short)f2bf(f3.z); u1[7]=(short)f2bf(f3.w);
            } else {
                const bf16x8* s = (const bf16x8*)(inputs +
                    ((size_t)n*B_TOT + c0 + row0 + arow)*32 + aseg*16);
                u0 = s[0]; u1 = s[1];
            }
        } else {
            const unsigned short* s = Asrc + ((size_t)n*Bc + row0 + arow)*ASTR + k0 + aseg*16;
            u0 = ((const bf16x8*)s)[0];
            u1 = ((const bf16x8*)s)[1];
        }
    };
    auto loadW = [&](int k0, bf16x8 &u0, bf16x8 &u1) {
        const unsigned short* s = Wp + ((size_t)n*M + col0 + wrow)*(size_t)KW + k0 + (wkb >> 1);
        u0 = ((const bf16x8*)s)[0];
        if (TN == 128) u1 = ((const bf16x8*)s)[1];
    };

    loadA(0, au0, au1);
    loadW(0, wu0, wu1);

    for (int tt = 0; tt < NT; ++tt) {
        char* A_ = (char*)&As[tt & 1][0];
        char* W_ = (char*)&Ws[tt & 1][0];
        *(bf16x8*)(A_ + swz(arow, aseg*32))      = au0;
        *(bf16x8*)(A_ + swz(arow, aseg*32 + 16)) = au1;
        *(bf16x8*)(W_ + swz(wrow, wkb))          = wu0;
        if (TN == 128) *(bf16x8*)(W_ + swz(wrow, wkb + 16)) = wu1;
        __syncthreads();
        if (tt + 1 < NT) {
            loadA((tt+1)*32, au0, au1);
            loadW((tt+1)*32, wu0, wu1);
        }
        bf16x8 a0 = *(bf16x8*)(A_ + swz(w*32 + lr,      lk*16));
        bf16x8 a1 = *(bf16x8*)(A_ + swz(w*32 + 16 + lr, lk*16));
        bf16x8 bq[NJ];
        #pragma unroll
        for (int j = 0; j < NJ; ++j)
            bq[j] = *(bf16x8*)(W_ + swz(j*16 + lr, lk*16));
        #pragma unroll
        for (int j = 0; j < NJ; ++j)
            acc[0][j] = __builtin_amdgcn_mfma_f32_16x16x32_bf16(a0, bq[j], acc[0][j], 0, 0, 0);
        #pragma unroll
        for (int j = 0; j < NJ; ++j)
            acc[1][j] = __builtin_amdgcn_mfma_f32_16x16x32_bf16(a1, bq[j], acc[1][j], 0, 0, 0);
    }

    if constexpr (MODE == 0) {
        #pragma unroll
        for (int i = 0; i < 2; ++i) {
            int rbase = row0 + w*32 + i*16 + lk*4;
            #pragma unroll
            for (int half = 0; half < 2; ++half) {
                int o = (col0 >> 2) + half*16 + lr;
                #pragma unroll
                for (int reg = 0; reg < 4; ++reg) {
                    int r = rbase + reg;
                    float rs = acc[i][0+half][reg];
                    float zs = acc[i][2+half][reg];
                    float gx = acc[i][4+half][reg];
                    float gh = acc[i][6+half][reg];
                    float hold = hs_glob[(((size_t)(c0 + r))*NU + n)*HH + o];
                    float rr = sigm(rs), z = sigm(zs);
                    float nn = tanhf(gx + rr*gh);
                    float h  = nn + z*(hold - nn);
                    hsnb[((size_t)n*Bc + r)*256 + o] = f2bf(h);
                }
            }
        }
    } else if constexpr (MODE == 1) {
        #pragma unroll
        for (int i = 0; i < 2; ++i) {
            #pragma unroll
            for (int j = 0; j < NJ; ++j) {
                int c = col0 + j*16 + lr;
                #pragma unroll
                for (int reg = 0; reg < 4; ++reg) {
                    int r = row0 + w*32 + i*16 + lk*4 + reg;
                    QKV[((size_t)n*Bc + r)*1152 + c] = f2bf(acc[i][j][reg]);
                }
            }
        }
    } else {
        #pragma unroll
        for (int i = 0; i < 2; ++i) {
            #pragma unroll
            for (int reg = 0; reg < 4; ++reg) {
                int r = row0 + w*32 + i*16 + lk*4 + reg;
                float mkv = maskf[(size_t)(c0 + r)*8 + n];
                #pragma unroll
                for (int j = 0; j < NJ; ++j) {
                    int c = col0 + j*16 + lr;
                    size_t gi = (((size_t)(c0 + r))*NU + n)*HH + c;
                    float v;
                    if (mkv != 0.f) v = acc[i][j][reg] + bf2f(hsnb[((size_t)n*Bc + r)*256 + c]);
                    else            v = hs_glob[gi];
                    outp[gi] = v;
                }
            }
        }
    }
}

extern "C" void kernel_launch(void* const* d_in, const int* in_sizes, int n_in,
                              void* d_out, int out_size, void* d_ws, size_t ws_size,
                              hipStream_t stream)
{
    const float* x1   = (const float*)d_in[0];
    const float* x2   = (const float*)d_in[1];
    const float* hs   = (const float*)d_in[2];
    const float* Wkey = (const float*)d_in[3];
    const float* bkey = (const float*)d_in[4];
    const float* Wval = (const float*)d_in[5];
    const float* bval = (const float*)d_in[6];
    const float* Wq   = (const float*)d_in[7];
    const float* Wq_  = (const float*)d_in[8];
    const float* Wk_  = (const float*)d_in[9];
    const float* Wv_  = (const float*)d_in[10];
    const float* Wout = (const float*)d_in[11];
    const float* Wx2h = (const float*)d_in[12];
    const float* Wh2h = (const float*)d_in[13];
    float* out = (float*)d_out;

    char* ws = (char*)d_ws;
    size_t off = 0;
    auto alloc = [&](size_t bytes) -> void* {
        void* p = (void*)(ws + off);
        off = (off + bytes + 255) & ~(size_t)255;
        return p;
    };
    unsigned short* Wg     = (unsigned short*)alloc((size_t)8*1024*288*2);
    unsigned short* Wqkv   = (unsigned short*)alloc((size_t)8*1152*256*2);
    unsigned short* WoutT  = (unsigned short*)alloc((size_t)8*256*1024*2);
    unsigned short* Wkv    = (unsigned short*)alloc((size_t)48*256*2);
    unsigned short* Wqt    = (unsigned short*)alloc((size_t)8*16*256*2);
    unsigned short* inputs = (unsigned short*)alloc((size_t)8*B_TOT*32*2);
    float*          maskf  = (float*)         alloc((size_t)B_TOT*8*4);
    float*          KV     = (float*)         alloc((size_t)2*B_TOT*48*4);
    float*          qL     = (float*)         alloc((size_t)8*B_TOT*16*4);
    size_t persist = off;

    const size_t perB = 8*256*2 + 8*1152*2;   // hsnb + QKV
    int Bc = B_TOT;
    while (Bc > 128 && persist + (size_t)Bc*perB + 65536 > ws_size) Bc >>= 1;
    unsigned short* hsnb = (unsigned short*)alloc((size_t)8*Bc*256*2);
    unsigned short* QKV  = (unsigned short*)alloc((size_t)8*Bc*1152*2);

    pack_gates<<<(8*1024*288 + 255)/256, 256, 0, stream>>>(Wh2h, Wx2h, Wg);
    pack_qkv  <<<(8*1152*256 + 255)/256, 256, 0, stream>>>(Wq_, Wk_, Wv_, Wqkv);
    pack_out  <<<(8*256*1024 + 255)/256, 256, 0, stream>>>(Wout, WoutT);
    pack_kvw  <<<(48*256 + 255)/256, 256, 0, stream>>>(Wkey, Wval, Wkv);
    pack_qlw  <<<(8*16*256 + 255)/256, 256, 0, stream>>>(Wq, Wqt);

    small_gemm<0><<<dim3(2*B_TOT/128), 256, 0, stream>>>(x1, x2, Wkv, KV);
    small_gemm<1><<<dim3(B_TOT/128, 8), 256, 0, stream>>>(hs, nullptr, Wqt, qL);
    score_mask_inputs<<<B_TOT/32, 256, 0, stream>>>(KV, qL, bkey, bval, inputs, maskf);

    for (int c0 = 0; c0 < B_TOT; c0 += Bc) {
        int RB = Bc / 128;
        gemm_mfma<0,128><<<dim3(RB*8*8), 256, 0, stream>>>(
            hs, inputs, nullptr, Wg, hsnb, nullptr, nullptr, nullptr, Bc, c0);
        gemm_mfma<1,128><<<dim3(RB*9*8), 256, 0, stream>>>(
            hs, nullptr, hsnb, Wqkv, nullptr, QKV, nullptr, nullptr, Bc, c0);
        attn_kernel<<<Bc/4, 256, 0, stream>>>(QKV, maskf, Bc, c0);
        gemm_mfma<2,64><<<dim3(RB*4*8), 256, 0, stream>>>(
            hs, nullptr, QKV + 64, WoutT, hsnb, nullptr, maskf, out, Bc, c0);
    }
}

// Round 5
// 385.167 us; speedup vs baseline: 4.7797x; 1.2180x over previous
//
#include <hip/hip_runtime.h>
#include <math.h>

// BRIMCell forward — bf16 MFMA everywhere GEMM-shaped; fused GRU; col-fastest
// block ordering (W panel L2-resident, A fetched once); hs pre-converted to
// bf16 (hsb) inside the qL small-GEMM. B=8192, N=8, H=D=256.

#define B_TOT 8192
#define NU 8
#define HH 256

typedef __attribute__((ext_vector_type(8))) short bf16x8;
typedef __attribute__((ext_vector_type(4))) float f32x4;

__device__ __forceinline__ float sigm(float x){ return 1.0f/(1.0f+expf(-x)); }

__device__ __forceinline__ unsigned short f2bf(float f){
    union { float f; unsigned int u; } v; v.f = f;
    unsigned int r = v.u + 0x7fffu + ((v.u >> 16) & 1u);
    return (unsigned short)(r >> 16);
}
__device__ __forceinline__ float bf2f(unsigned short h){
    union { unsigned int u; float f; } v; v.u = ((unsigned int)h) << 16;
    return v.f;
}

// LDS tile: 64B rows (32 bf16), 16B slots, XOR swizzle (bijective per 512B group).
__device__ __forceinline__ int swz(int row, int kb){
    return (row*64 + kb) ^ ((row & 7) << 4);
}

// ---------- weight packing (transposed [n][col][k], bf16) ----------
__global__ void pack_gates(const float* __restrict__ Wh2h, const float* __restrict__ Wx2h,
                           unsigned short* __restrict__ Wg)
{
    int idx = blockIdx.x*256 + threadIdx.x;
    const int total = 8*1024*288;
    if (idx >= total) return;
    int k  = idx % 288;
    int pc = (idx / 288) % 1024;
    int n  = idx / (288*1024);
    int cb = pc >> 7, r = pc & 127;
    int g = r >> 5, ol = r & 31;
    int o = cb*32 + ol;
    float v = 0.f;
    if (g == 0)      v = (k < 256) ? Wh2h[((size_t)n*256 + k)*768 + o]
                                   : Wx2h[((size_t)n*32 + (k-256))*768 + o];
    else if (g == 1) v = (k < 256) ? Wh2h[((size_t)n*256 + k)*768 + 256 + o]
                                   : Wx2h[((size_t)n*32 + (k-256))*768 + 256 + o];
    else if (g == 2) v = (k >= 256) ? Wx2h[((size_t)n*32 + (k-256))*768 + 512 + o] : 0.f;
    else             v = (k < 256) ? Wh2h[((size_t)n*256 + k)*768 + 512 + o] : 0.f;
    Wg[idx] = f2bf(v);
}

__global__ void pack_qkv(const float* __restrict__ Wq_, const float* __restrict__ Wk_,
                         const float* __restrict__ Wv_, unsigned short* __restrict__ Wqkv)
{
    int idx = blockIdx.x*256 + threadIdx.x;
    const int total = 8*1152*256;
    if (idx >= total) return;
    int k = idx % 256;
    int c = (idx / 256) % 1152;
    int n = idx / (256*1152);
    float v = 0.f;
    if (c < 32)        v = Wq_[((size_t)n*256+k)*32 + c];
    else if (c < 64)   v = Wk_[((size_t)n*256+k)*32 + (c-32)];
    else if (c < 1088) v = Wv_[((size_t)n*256+k)*1024 + (c-64)];
    Wqkv[idx] = f2bf(v);
}

__global__ void pack_out(const float* __restrict__ Wout, unsigned short* __restrict__ Wt)
{
    int idx = blockIdx.x*256 + threadIdx.x;
    const int total = 8*256*1024;
    if (idx >= total) return;
    int k = idx % 1024;
    int c = (idx / 1024) % 256;
    int n = idx / (1024*256);
    Wt[idx] = f2bf(Wout[((size_t)n*1024 + k)*256 + c]);
}

__global__ void pack_kvw(const float* __restrict__ Wkey, const float* __restrict__ Wval,
                         unsigned short* __restrict__ Wkv)
{
    int idx = blockIdx.x*256 + threadIdx.x;
    if (idx >= 48*256) return;
    int k = idx & 255, c = idx >> 8;
    float v = (c < 16) ? Wkey[k*16 + c] : Wval[k*32 + (c-16)];
    Wkv[(size_t)c*256 + k] = f2bf(v);
}

__global__ void pack_qlw(const float* __restrict__ Wq, unsigned short* __restrict__ Wqt)
{
    int idx = blockIdx.x*256 + threadIdx.x;
    if (idx >= 8*16*256) return;
    int k = idx & 255, c = (idx >> 8) & 15, n = idx >> 12;
    Wqt[((size_t)n*16 + c)*256 + k] = f2bf(Wq[((size_t)n*256 + k)*16 + c]);
}

// ---------- small MFMA GEMM for stage-A precursors ----------
// SRC 0: KV[16384][48] = [x1;x2](fp32) @ Wkv^T, M=48
// SRC 1: qL[n][8192][16] = hs_unit(fp32) @ Wqt[n]^T, M=16; also writes hsb bf16
template<int SRC>
__global__ __launch_bounds__(256) void small_gemm(
    const float* __restrict__ A0, const float* __restrict__ A1,
    const unsigned short* __restrict__ Wp, float* __restrict__ C,
    unsigned short* __restrict__ hsb)
{
    constexpr int M  = (SRC == 0) ? 48 : 16;
    constexpr int NJ = M/16;
    int row0 = blockIdx.x * 128;
    int n = (SRC == 1) ? blockIdx.y : 0;
    const unsigned short* W = Wp + (size_t)n*M*256;

    __shared__ unsigned short As[2][128*32];
    __shared__ unsigned short Ws[2][M*32];

    int t = threadIdx.x, l = t & 63, w = t >> 6;
    int lr = l & 15, lk = l >> 4;
    int arow = t >> 1, aseg = t & 1;

    f32x4 acc[2][NJ];
    #pragma unroll
    for (int i = 0; i < 2; ++i)
        #pragma unroll
        for (int j = 0; j < NJ; ++j)
            acc[i][j] = (f32x4){0.f,0.f,0.f,0.f};

    bf16x8 au0, au1, wu0, wu1;
    auto loadA = [&](int k0, bf16x8 &u0, bf16x8 &u1) {
        const float* src;
        if (SRC == 0) {
            int gr = row0 + arow;
            src = (gr < B_TOT ? A0 + (size_t)gr*HH : A1 + (size_t)(gr - B_TOT)*HH) + k0 + aseg*16;
        } else {
            src = A0 + (((size_t)(row0 + arow))*NU + n)*HH + k0 + aseg*16;
        }
        const float4* s4 = (const float4*)src;
        float4 f0 = s4[0], f1 = s4[1], f2 = s4[2], f3 = s4[3];
        u0[0]=(short)f2bf(f0.x); u0[1]=(short)f2bf(f0.y); u0[2]=(short)f2bf(f0.z); u0[3]=(short)f2bf(f0.w);
        u0[4]=(short)f2bf(f1.x); u0[5]=(short)f2bf(f1.y); u0[6]=(short)f2bf(f1.z); u0[7]=(short)f2bf(f1.w);
        u1[0]=(short)f2bf(f2.x); u1[1]=(short)f2bf(f2.y); u1[2]=(short)f2bf(f2.z); u1[3]=(short)f2bf(f2.w);
        u1[4]=(short)f2bf(f3.x); u1[5]=(short)f2bf(f3.y); u1[6]=(short)f2bf(f3.z); u1[7]=(short)f2bf(f3.w);
        if (SRC == 1) {   // persist bf16 hs for the downstream GEMMs
            unsigned short* dp = hsb + ((size_t)n*B_TOT + row0 + arow)*256 + k0 + aseg*16;
            *(bf16x8*)dp       = u0;
            *(bf16x8*)(dp + 8) = u1;
        }
    };
    auto loadW = [&](int k0, bf16x8 &u0, bf16x8 &u1) {
        if (t < M*2) {
            const unsigned short* s = W + (size_t)(t >> 1)*256 + k0 + (t & 1)*16;
            u0 = ((const bf16x8*)s)[0];
            u1 = ((const bf16x8*)s)[1];
        }
    };

    loadA(0, au0, au1);
    loadW(0, wu0, wu1);

    for (int tt = 0; tt < 8; ++tt) {
        char* A_ = (char*)&As[tt & 1][0];
        char* W_ = (char*)&Ws[tt & 1][0];
        *(bf16x8*)(A_ + swz(arow, aseg*32))      = au0;
        *(bf16x8*)(A_ + swz(arow, aseg*32 + 16)) = au1;
        if (t < M*2) {
            *(bf16x8*)(W_ + swz(t >> 1, (t & 1)*32))      = wu0;
            *(bf16x8*)(W_ + swz(t >> 1, (t & 1)*32 + 16)) = wu1;
        }
        __syncthreads();
        if (tt + 1 < 8) {
            loadA((tt+1)*32, au0, au1);
            loadW((tt+1)*32, wu0, wu1);
        }
        bf16x8 a0 = *(bf16x8*)(A_ + swz(w*32 + lr,      lk*16));
        bf16x8 a1 = *(bf16x8*)(A_ + swz(w*32 + 16 + lr, lk*16));
        bf16x8 bq[NJ];
        #pragma unroll
        for (int j = 0; j < NJ; ++j)
            bq[j] = *(bf16x8*)(W_ + swz(j*16 + lr, lk*16));
        #pragma unroll
        for (int j = 0; j < NJ; ++j) {
            acc[0][j] = __builtin_amdgcn_mfma_f32_16x16x32_bf16(a0, bq[j], acc[0][j], 0, 0, 0);
            acc[1][j] = __builtin_amdgcn_mfma_f32_16x16x32_bf16(a1, bq[j], acc[1][j], 0, 0, 0);
        }
    }

    float* Cb = (SRC == 0) ? C : C + (size_t)n*B_TOT*16;
    #pragma unroll
    for (int i = 0; i < 2; ++i)
        #pragma unroll
        for (int j = 0; j < NJ; ++j)
            #pragma unroll
            for (int reg = 0; reg < 4; ++reg) {
                int r = row0 + w*32 + i*16 + lk*4 + reg;
                Cb[(size_t)r*M + j*16 + lr] = acc[i][j][reg];
            }
}

// ---------- scores -> softmax -> mask -> inputs (1 thread per (batch,unit)) ----------
__global__ __launch_bounds__(256) void score_mask_inputs(
    const float* __restrict__ KV,   // [16384][48]
    const float* __restrict__ qL,   // [8][8192][16]
    const float* __restrict__ bkey, const float* __restrict__ bval,
    unsigned short* __restrict__ inputs, float* __restrict__ maskf)
{
    int t  = threadIdx.x;
    int gb = blockIdx.x*32 + (t >> 3);
    int n  = t & 7, l = t & 63;

    float q[16];
    const float* qp = qL + ((size_t)n*B_TOT + gb)*16;
    #pragma unroll
    for (int i = 0; i < 4; ++i) *(float4*)&q[i*4] = ((const float4*)qp)[i];

    const float* kv0 = KV + (size_t)gb*48;
    const float* kv1 = KV + (size_t)(B_TOT + gb)*48;

    float s0 = 0.f, s1 = 0.f, sn = 0.f;
    #pragma unroll
    for (int k = 0; k < 16; ++k) {
        float bk = bkey[k];
        s0 += q[k]*(kv0[k] + bk);
        s1 += q[k]*(kv1[k] + bk);
        sn += q[k]*bk;
    }
    s0 *= 0.25f; s1 *= 0.25f; sn *= 0.25f;

    float mx = fmaxf(s0, fmaxf(s1, sn));
    float e0 = expf(s0-mx), e1 = expf(s1-mx), en = expf(sn-mx);
    float inv = 1.f/(e0+e1+en);
    float p0 = e0*inv, p1 = e1*inv, pn = en*inv;

    int rank = 0;
    #pragma unroll
    for (int m = 0; m < 8; ++m) {
        float sm = __shfl(sn, (l & ~7) + m, 64);
        if (sm > sn || (sm == sn && m < n)) rank++;
    }
    float mk = (rank < 4) ? 0.f : 1.f;
    maskf[(size_t)gb*8 + n] = mk;

    unsigned short* op = inputs + ((size_t)n*B_TOT + gb)*32;
    #pragma unroll
    for (int db = 0; db < 4; ++db) {
        bf16x8 o;
        #pragma unroll
        for (int e = 0; e < 8; ++e) {
            int d = db*8 + e;
            float bv = bval[d];
            float v = mk*(p0*(kv0[16+d]+bv) + p1*(kv1[16+d]+bv) + pn*bv);
            o[e] = (short)f2bf(v);
        }
        *(bf16x8*)&op[db*8] = o;
    }
}

// ---------- per-batch 4-head attention; 4 batches/block; ctx in-place over v2 ----------
__global__ __launch_bounds__(256) void attn_kernel(
    unsigned short* __restrict__ QKV, const float* __restrict__ maskf, int Bc, int c0)
{
    int wid = threadIdx.x >> 6;
    int l   = threadIdx.x & 63;
    int b   = blockIdx.x*4 + wid;
    int gb  = c0 + b;

    __shared__ float qk[4][8][64];
    __shared__ float P[4][4][8][8];

    for (int it = 0; it < 8; ++it) {
        int idx = l + 64*it;
        int n = idx >> 6, c = idx & 63;
        qk[wid][n][c] = bf2f(QKV[((size_t)n*Bc + b)*1152 + c]);
    }
    __syncthreads();

    for (int it = 0; it < 4; ++it) {
        int idx = l + 64*it;
        int h = idx >> 6, n = (idx >> 3) & 7, m = idx & 7;
        float s = 0.f;
        #pragma unroll
        for (int dk = 0; dk < 8; ++dk) s += qk[wid][n][h*8 + dk]*qk[wid][m][32 + h*8 + dk];
        P[wid][h][n][m] = s * 0.35355339059327373f;
    }
    __syncthreads();

    if (l < 32) {
        int h = l >> 3, n = l & 7;
        float mx = -1e30f;
        for (int m = 0; m < 8; ++m) mx = fmaxf(mx, P[wid][h][n][m]);
        float e[8], sum = 0.f;
        for (int m = 0; m < 8; ++m) { e[m] = expf(P[wid][h][n][m]-mx); sum += e[m]; }
        float scl = maskf[(size_t)gb*8 + n] / sum;
        for (int m = 0; m < 8; ++m) P[wid][h][n][m] = e[m]*scl;
    }
    __syncthreads();

    #pragma unroll
    for (int it = 0; it < 2; ++it) {
        int colb = (l + 64*it)*8;
        int h = colb >> 8;
        float acc[8][8];
        #pragma unroll
        for (int n = 0; n < 8; ++n)
            #pragma unroll
            for (int c = 0; c < 8; ++c) acc[n][c] = 0.f;
        for (int m = 0; m < 8; ++m) {
            bf16x8 v8 = *(const bf16x8*)&QKV[((size_t)m*Bc + b)*1152 + 64 + colb];
            float vf[8];
            #pragma unroll
            for (int c = 0; c < 8; ++c) vf[c] = bf2f((unsigned short)v8[c]);
            #pragma unroll
            for (int n = 0; n < 8; ++n) {
                float p = P[wid][h][n][m];
                #pragma unroll
                for (int c = 0; c < 8; ++c) acc[n][c] += p*vf[c];
            }
        }
        #pragma unroll
        for (int n = 0; n < 8; ++n) {
            bf16x8 o;
            #pragma unroll
            for (int c = 0; c < 8; ++c) o[c] = (short)f2bf(acc[n][c]);
            *(bf16x8*)&QKV[((size_t)n*Bc + b)*1152 + 64 + colb] = o;
        }
    }
}

// ---------- MFMA GEMM, dbuf+prefetch, n->XCD, col-block fastest ----------
// MODE 0: gates+GRU fused (A = hsb|inputs). MODE 1: qkv. MODE 2: out + epilogue.
template<int MODE, int TN>
__global__ __launch_bounds__(256) void gemm_mfma(
    const float* __restrict__ hs_glob,
    const unsigned short* __restrict__ hsb,
    const unsigned short* __restrict__ inputs,
    const unsigned short* __restrict__ Asrc,
    const unsigned short* __restrict__ Wp,
    unsigned short* __restrict__ hsnb,
    unsigned short* __restrict__ QKV,
    const float* __restrict__ maskf,
    float* __restrict__ outp,
    int Bc, int c0)
{
    constexpr int KW   = (MODE==0) ? 288 : (MODE==1 ? 256 : 1024);
    constexpr int M    = (MODE==0) ? 1024 : (MODE==1 ? 1152 : 256);
    constexpr int NJ   = TN/16;
    constexpr int NT   = KW/32;
    constexpr int ASTR = (MODE==2) ? 1152 : 256;
    constexpr int CB   = M/TN;

    int bid = blockIdx.x;
    int n   = bid & 7;                 // unit == XCD: W panel stays in one L2
    int loc = bid >> 3;
    int col0 = (loc % CB) * TN;        // cols fastest: A row-tile reused in L2
    int row0 = (loc / CB) * 128;

    __shared__ unsigned short As[2][128*32];
    __shared__ unsigned short Ws[2][TN*32];

    int t = threadIdx.x;
    int l = t & 63, w = t >> 6;
    int lr = l & 15, lk = l >> 4;

    int arow = t >> 1, aseg = t & 1;
    int wrow, wkb;
    if (TN == 128) { wrow = t >> 1; wkb = (t & 1) * 32; }
    else           { wrow = t >> 2; wkb = (t & 3) * 16; }

    f32x4 acc[2][NJ];
    #pragma unroll
    for (int i = 0; i < 2; ++i)
        #pragma unroll
        for (int j = 0; j < NJ; ++j)
            acc[i][j] = (f32x4){0.f,0.f,0.f,0.f};

    bf16x8 au0, au1, wu0, wu1;

    auto loadA = [&](int k0, bf16x8 &u0, bf16x8 &u1) {
        const unsigned short* s;
        if (MODE == 0) {
            if (k0 < 256) s = hsb + ((size_t)n*B_TOT + c0 + row0 + arow)*256 + k0 + aseg*16;
            else          s = inputs + ((size_t)n*B_TOT + c0 + row0 + arow)*32 + aseg*16;
        } else {
            s = Asrc + ((size_t)n*Bc + row0 + arow)*ASTR + k0 + aseg*16;
        }
        u0 = ((const bf16x8*)s)[0];
        u1 = ((const bf16x8*)s)[1];
    };
    auto loadW = [&](int k0, bf16x8 &u0, bf16x8 &u1) {
        const unsigned short* s = Wp + ((size_t)n*M + col0 + wrow)*(size_t)KW + k0 + (wkb >> 1);
        u0 = ((const bf16x8*)s)[0];
        if (TN == 128) u1 = ((const bf16x8*)s)[1];
    };

    loadA(0, au0, au1);
    loadW(0, wu0, wu1);

    for (int tt = 0; tt < NT; ++tt) {
        char* A_ = (char*)&As[tt & 1][0];
        char* W_ = (char*)&Ws[tt & 1][0];
        *(bf16x8*)(A_ + swz(arow, aseg*32))      = au0;
        *(bf16x8*)(A_ + swz(arow, aseg*32 + 16)) = au1;
        *(bf16x8*)(W_ + swz(wrow, wkb))          = wu0;
        if (TN == 128) *(bf16x8*)(W_ + swz(wrow, wkb + 16)) = wu1;
        __syncthreads();
        if (tt + 1 < NT) {
            loadA((tt+1)*32, au0, au1);
            loadW((tt+1)*32, wu0, wu1);
        }
        bf16x8 a0 = *(bf16x8*)(A_ + swz(w*32 + lr,      lk*16));
        bf16x8 a1 = *(bf16x8*)(A_ + swz(w*32 + 16 + lr, lk*16));
        bf16x8 bq[NJ];
        #pragma unroll
        for (int j = 0; j < NJ; ++j)
            bq[j] = *(bf16x8*)(W_ + swz(j*16 + lr, lk*16));
        #pragma unroll
        for (int j = 0; j < NJ; ++j)
            acc[0][j] = __builtin_amdgcn_mfma_f32_16x16x32_bf16(a0, bq[j], acc[0][j], 0, 0, 0);
        #pragma unroll
        for (int j = 0; j < NJ; ++j)
            acc[1][j] = __builtin_amdgcn_mfma_f32_16x16x32_bf16(a1, bq[j], acc[1][j], 0, 0, 0);
    }

    if constexpr (MODE == 0) {
        #pragma unroll
        for (int i = 0; i < 2; ++i) {
            int rbase = row0 + w*32 + i*16 + lk*4;
            #pragma unroll
            for (int half = 0; half < 2; ++half) {
                int o = (col0 >> 2) + half*16 + lr;
                #pragma unroll
                for (int reg = 0; reg < 4; ++reg) {
                    int r = rbase + reg;
                    float rs = acc[i][0+half][reg];
                    float zs = acc[i][2+half][reg];
                    float gx = acc[i][4+half][reg];
                    float gh = acc[i][6+half][reg];
                    float hold = bf2f(hsb[((size_t)n*B_TOT + c0 + r)*256 + o]);
                    float rr = sigm(rs), z = sigm(zs);
                    float nn = tanhf(gx + rr*gh);
                    float h  = nn + z*(hold - nn);
                    hsnb[((size_t)n*Bc + r)*256 + o] = f2bf(h);
                }
            }
        }
    } else if constexpr (MODE == 1) {
        #pragma unroll
        for (int i = 0; i < 2; ++i) {
            #pragma unroll
            for (int j = 0; j < NJ; ++j) {
                int c = col0 + j*16 + lr;
                #pragma unroll
                for (int reg = 0; reg < 4; ++reg) {
                    int r = row0 + w*32 + i*16 + lk*4 + reg;
                    QKV[((size_t)n*Bc + r)*1152 + c] = f2bf(acc[i][j][reg]);
                }
            }
        }
    } else {
        #pragma unroll
        for (int i = 0; i < 2; ++i) {
            #pragma unroll
            for (int reg = 0; reg < 4; ++reg) {
                int r = row0 + w*32 + i*16 + lk*4 + reg;
                float mkv = maskf[(size_t)(c0 + r)*8 + n];
                #pragma unroll
                for (int j = 0; j < NJ; ++j) {
                    int c = col0 + j*16 + lr;
                    size_t gi = (((size_t)(c0 + r))*NU + n)*HH + c;
                    float v;
                    if (mkv != 0.f) v = acc[i][j][reg] + bf2f(hsnb[((size_t)n*Bc + r)*256 + c]);
                    else            v = hs_glob[gi];
                    outp[gi] = v;
                }
            }
        }
    }
}

extern "C" void kernel_launch(void* const* d_in, const int* in_sizes, int n_in,
                              void* d_out, int out_size, void* d_ws, size_t ws_size,
                              hipStream_t stream)
{
    const float* x1   = (const float*)d_in[0];
    const float* x2   = (const float*)d_in[1];
    const float* hs   = (const float*)d_in[2];
    const float* Wkey = (const float*)d_in[3];
    const float* bkey = (const float*)d_in[4];
    const float* Wval = (const float*)d_in[5];
    const float* bval = (const float*)d_in[6];
    const float* Wq   = (const float*)d_in[7];
    const float* Wq_  = (const float*)d_in[8];
    const float* Wk_  = (const float*)d_in[9];
    const float* Wv_  = (const float*)d_in[10];
    const float* Wout = (const float*)d_in[11];
    const float* Wx2h = (const float*)d_in[12];
    const float* Wh2h = (const float*)d_in[13];
    float* out = (float*)d_out;

    char* ws = (char*)d_ws;
    size_t off = 0;
    auto alloc = [&](size_t bytes) -> void* {
        void* p = (void*)(ws + off);
        off = (off + bytes + 255) & ~(size_t)255;
        return p;
    };
    unsigned short* Wg     = (unsigned short*)alloc((size_t)8*1024*288*2);
    unsigned short* Wqkv   = (unsigned short*)alloc((size_t)8*1152*256*2);
    unsigned short* WoutT  = (unsigned short*)alloc((size_t)8*256*1024*2);
    unsigned short* Wkv    = (unsigned short*)alloc((size_t)48*256*2);
    unsigned short* Wqt    = (unsigned short*)alloc((size_t)8*16*256*2);
    unsigned short* inputs = (unsigned short*)alloc((size_t)8*B_TOT*32*2);
    float*          maskf  = (float*)         alloc((size_t)B_TOT*8*4);
    float*          KV     = (float*)         alloc((size_t)2*B_TOT*48*4);
    float*          qL     = (float*)         alloc((size_t)8*B_TOT*16*4);
    unsigned short* hsb    = (unsigned short*)alloc((size_t)8*B_TOT*256*2);
    size_t persist = off;

    const size_t perB = 8*256*2 + 8*1152*2;   // hsnb + QKV
    int Bc = B_TOT;
    while (Bc > 128 && persist + (size_t)Bc*perB + 65536 > ws_size) Bc >>= 1;
    unsigned short* hsnb = (unsigned short*)alloc((size_t)8*Bc*256*2);
    unsigned short* QKV  = (unsigned short*)alloc((size_t)8*Bc*1152*2);

    pack_gates<<<(8*1024*288 + 255)/256, 256, 0, stream>>>(Wh2h, Wx2h, Wg);
    pack_qkv  <<<(8*1152*256 + 255)/256, 256, 0, stream>>>(Wq_, Wk_, Wv_, Wqkv);
    pack_out  <<<(8*256*1024 + 255)/256, 256, 0, stream>>>(Wout, WoutT);
    pack_kvw  <<<(48*256 + 255)/256, 256, 0, stream>>>(Wkey, Wval, Wkv);
    pack_qlw  <<<(8*16*256 + 255)/256, 256, 0, stream>>>(Wq, Wqt);

    small_gemm<0><<<dim3(2*B_TOT/128), 256, 0, stream>>>(x1, x2, Wkv, KV, nullptr);
    small_gemm<1><<<dim3(B_TOT/128, 8), 256, 0, stream>>>(hs, nullptr, Wqt, qL, hsb);
    score_mask_inputs<<<B_TOT/32, 256, 0, stream>>>(KV, qL, bkey, bval, inputs, maskf);

    for (int c0 = 0; c0 < B_TOT; c0 += Bc) {
        int RB = Bc / 128;
        gemm_mfma<0,128><<<dim3(RB*8*8), 256, 0, stream>>>(
            hs, hsb, inputs, nullptr, Wg, hsnb, nullptr, nullptr, nullptr, Bc, c0);
        gemm_mfma<1,128><<<dim3(RB*9*8), 256, 0, stream>>>(
            hs, hsb, nullptr, hsnb, Wqkv, nullptr, QKV, nullptr, nullptr, Bc, c0);
        attn_kernel<<<Bc/4, 256, 0, stream>>>(QKV, maskf, Bc, c0);
        gemm_mfma<2,64><<<dim3(RB*4*8), 256, 0, stream>>>(
            hs, hsb, nullptr, QKV + 64, WoutT, hsnb, nullptr, maskf, out, Bc, c0);
    }
}

// Round 6
// 357.474 us; speedup vs baseline: 5.1500x; 1.0775x over previous
//
#include <hip/hip_runtime.h>
#include <math.h>

// BRIMCell forward — bf16 MFMA GEMMs; fused GRU; n->XCD + col-fastest ordering;
// 2-deep register prefetch; back-half chunked (Bc=4096) for L3 residency.
// B=8192, N=8, H=D=256.

#define B_TOT 8192
#define NU 8
#define HH 256

typedef __attribute__((ext_vector_type(8))) short bf16x8;
typedef __attribute__((ext_vector_type(4))) float f32x4;

__device__ __forceinline__ float sigm(float x){ return 1.0f/(1.0f+expf(-x)); }

__device__ __forceinline__ unsigned short f2bf(float f){
    union { float f; unsigned int u; } v; v.f = f;
    unsigned int r = v.u + 0x7fffu + ((v.u >> 16) & 1u);
    return (unsigned short)(r >> 16);
}
__device__ __forceinline__ float bf2f(unsigned short h){
    union { unsigned int u; float f; } v; v.u = ((unsigned int)h) << 16;
    return v.f;
}

// LDS tile: 64B rows (32 bf16), 16B slots, XOR swizzle (bijective: bits7,8 fixed,
// b6'=b6^b8, b5'=b5^b7, b4'=b4^b6' — recoverable top-down).
__device__ __forceinline__ int swz(int row, int kb){
    return (row*64 + kb) ^ ((row & 7) << 4);
}

// ---------- weight packing (transposed [n][col][k], bf16) ----------
__global__ void pack_gates(const float* __restrict__ Wh2h, const float* __restrict__ Wx2h,
                           unsigned short* __restrict__ Wg)
{
    int idx = blockIdx.x*256 + threadIdx.x;
    const int total = 8*1024*288;
    if (idx >= total) return;
    int k  = idx % 288;
    int pc = (idx / 288) % 1024;
    int n  = idx / (288*1024);
    int cb = pc >> 7, r = pc & 127;
    int g = r >> 5, ol = r & 31;
    int o = cb*32 + ol;
    float v = 0.f;
    if (g == 0)      v = (k < 256) ? Wh2h[((size_t)n*256 + k)*768 + o]
                                   : Wx2h[((size_t)n*32 + (k-256))*768 + o];
    else if (g == 1) v = (k < 256) ? Wh2h[((size_t)n*256 + k)*768 + 256 + o]
                                   : Wx2h[((size_t)n*32 + (k-256))*768 + 256 + o];
    else if (g == 2) v = (k >= 256) ? Wx2h[((size_t)n*32 + (k-256))*768 + 512 + o] : 0.f;
    else             v = (k < 256) ? Wh2h[((size_t)n*256 + k)*768 + 512 + o] : 0.f;
    Wg[idx] = f2bf(v);
}

__global__ void pack_qkv(const float* __restrict__ Wq_, const float* __restrict__ Wk_,
                         const float* __restrict__ Wv_, unsigned short* __restrict__ Wqkv)
{
    int idx = blockIdx.x*256 + threadIdx.x;
    const int total = 8*1152*256;
    if (idx >= total) return;
    int k = idx % 256;
    int c = (idx / 256) % 1152;
    int n = idx / (256*1152);
    float v = 0.f;
    if (c < 32)        v = Wq_[((size_t)n*256+k)*32 + c];
    else if (c < 64)   v = Wk_[((size_t)n*256+k)*32 + (c-32)];
    else if (c < 1088) v = Wv_[((size_t)n*256+k)*1024 + (c-64)];
    Wqkv[idx] = f2bf(v);
}

__global__ void pack_out(const float* __restrict__ Wout, unsigned short* __restrict__ Wt)
{
    int idx = blockIdx.x*256 + threadIdx.x;
    const int total = 8*256*1024;
    if (idx >= total) return;
    int k = idx % 1024;
    int c = (idx / 1024) % 256;
    int n = idx / (1024*256);
    Wt[idx] = f2bf(Wout[((size_t)n*1024 + k)*256 + c]);
}

__global__ void pack_kvw(const float* __restrict__ Wkey, const float* __restrict__ Wval,
                         unsigned short* __restrict__ Wkv)
{
    int idx = blockIdx.x*256 + threadIdx.x;
    if (idx >= 48*256) return;
    int k = idx & 255, c = idx >> 8;
    float v = (c < 16) ? Wkey[k*16 + c] : Wval[k*32 + (c-16)];
    Wkv[(size_t)c*256 + k] = f2bf(v);
}

__global__ void pack_qlw(const float* __restrict__ Wq, unsigned short* __restrict__ Wqt)
{
    int idx = blockIdx.x*256 + threadIdx.x;
    if (idx >= 8*16*256) return;
    int k = idx & 255, c = (idx >> 8) & 15, n = idx >> 12;
    Wqt[((size_t)n*16 + c)*256 + k] = f2bf(Wq[((size_t)n*256 + k)*16 + c]);
}

// ---------- small MFMA GEMM for stage-A precursors ----------
// SRC 0: KV[16384][48] = [x1;x2](fp32) @ Wkv^T, M=48
// SRC 1: qL[n][8192][16] = hs_unit(fp32) @ Wqt[n]^T, M=16; also writes hsb bf16
template<int SRC>
__global__ __launch_bounds__(256) void small_gemm(
    const float* __restrict__ A0, const float* __restrict__ A1,
    const unsigned short* __restrict__ Wp, float* __restrict__ C,
    unsigned short* __restrict__ hsb)
{
    constexpr int M  = (SRC == 0) ? 48 : 16;
    constexpr int NJ = M/16;
    int row0 = blockIdx.x * 128;
    int n = (SRC == 1) ? blockIdx.y : 0;
    const unsigned short* W = Wp + (size_t)n*M*256;

    __shared__ unsigned short As[2][128*32];
    __shared__ unsigned short Ws[2][M*32];

    int t = threadIdx.x, l = t & 63, w = t >> 6;
    int lr = l & 15, lk = l >> 4;
    int arow = t >> 1, aseg = t & 1;

    f32x4 acc[2][NJ];
    #pragma unroll
    for (int i = 0; i < 2; ++i)
        #pragma unroll
        for (int j = 0; j < NJ; ++j)
            acc[i][j] = (f32x4){0.f,0.f,0.f,0.f};

    bf16x8 au0, au1, wu0, wu1;
    auto loadA = [&](int k0, bf16x8 &u0, bf16x8 &u1) {
        const float* src;
        if (SRC == 0) {
            int gr = row0 + arow;
            src = (gr < B_TOT ? A0 + (size_t)gr*HH : A1 + (size_t)(gr - B_TOT)*HH) + k0 + aseg*16;
        } else {
            src = A0 + (((size_t)(row0 + arow))*NU + n)*HH + k0 + aseg*16;
        }
        const float4* s4 = (const float4*)src;
        float4 f0 = s4[0], f1 = s4[1], f2 = s4[2], f3 = s4[3];
        u0[0]=(short)f2bf(f0.x); u0[1]=(short)f2bf(f0.y); u0[2]=(short)f2bf(f0.z); u0[3]=(short)f2bf(f0.w);
        u0[4]=(short)f2bf(f1.x); u0[5]=(short)f2bf(f1.y); u0[6]=(short)f2bf(f1.z); u0[7]=(short)f2bf(f1.w);
        u1[0]=(short)f2bf(f2.x); u1[1]=(short)f2bf(f2.y); u1[2]=(short)f2bf(f2.z); u1[3]=(short)f2bf(f2.w);
        u1[4]=(short)f2bf(f3.x); u1[5]=(short)f2bf(f3.y); u1[6]=(short)f2bf(f3.z); u1[7]=(short)f2bf(f3.w);
        if (SRC == 1) {   // persist bf16 hs for the downstream GEMMs
            unsigned short* dp = hsb + ((size_t)n*B_TOT + row0 + arow)*256 + k0 + aseg*16;
            *(bf16x8*)dp       = u0;
            *(bf16x8*)(dp + 8) = u1;
        }
    };
    auto loadW = [&](int k0, bf16x8 &u0, bf16x8 &u1) {
        if (t < M*2) {
            const unsigned short* s = W + (size_t)(t >> 1)*256 + k0 + (t & 1)*16;
            u0 = ((const bf16x8*)s)[0];
            u1 = ((const bf16x8*)s)[1];
        }
    };

    loadA(0, au0, au1);
    loadW(0, wu0, wu1);

    for (int tt = 0; tt < 8; ++tt) {
        char* A_ = (char*)&As[tt & 1][0];
        char* W_ = (char*)&Ws[tt & 1][0];
        *(bf16x8*)(A_ + swz(arow, aseg*32))      = au0;
        *(bf16x8*)(A_ + swz(arow, aseg*32 + 16)) = au1;
        if (t < M*2) {
            *(bf16x8*)(W_ + swz(t >> 1, (t & 1)*32))      = wu0;
            *(bf16x8*)(W_ + swz(t >> 1, (t & 1)*32 + 16)) = wu1;
        }
        __syncthreads();
        if (tt + 1 < 8) {
            loadA((tt+1)*32, au0, au1);
            loadW((tt+1)*32, wu0, wu1);
        }
        bf16x8 a0 = *(bf16x8*)(A_ + swz(w*32 + lr,      lk*16));
        bf16x8 a1 = *(bf16x8*)(A_ + swz(w*32 + 16 + lr, lk*16));
        bf16x8 bq[NJ];
        #pragma unroll
        for (int j = 0; j < NJ; ++j)
            bq[j] = *(bf16x8*)(W_ + swz(j*16 + lr, lk*16));
        #pragma unroll
        for (int j = 0; j < NJ; ++j) {
            acc[0][j] = __builtin_amdgcn_mfma_f32_16x16x32_bf16(a0, bq[j], acc[0][j], 0, 0, 0);
            acc[1][j] = __builtin_amdgcn_mfma_f32_16x16x32_bf16(a1, bq[j], acc[1][j], 0, 0, 0);
        }
    }

    float* Cb = (SRC == 0) ? C : C + (size_t)n*B_TOT*16;
    #pragma unroll
    for (int i = 0; i < 2; ++i)
        #pragma unroll
        for (int j = 0; j < NJ; ++j)
            #pragma unroll
            for (int reg = 0; reg < 4; ++reg) {
                int r = row0 + w*32 + i*16 + lk*4 + reg;
                Cb[(size_t)r*M + j*16 + lr] = acc[i][j][reg];
            }
}

// ---------- scores -> softmax -> mask -> inputs (1 thread per (batch,unit)) ----------
__global__ __launch_bounds__(256) void score_mask_inputs(
    const float* __restrict__ KV,   // [16384][48]
    const float* __restrict__ qL,   // [8][8192][16]
    const float* __restrict__ bkey, const float* __restrict__ bval,
    unsigned short* __restrict__ inputs, float* __restrict__ maskf)
{
    int t  = threadIdx.x;
    int gb = blockIdx.x*32 + (t >> 3);
    int n  = t & 7, l = t & 63;

    float q[16];
    const float* qp = qL + ((size_t)n*B_TOT + gb)*16;
    #pragma unroll
    for (int i = 0; i < 4; ++i) *(float4*)&q[i*4] = ((const float4*)qp)[i];

    const float* kv0 = KV + (size_t)gb*48;
    const float* kv1 = KV + (size_t)(B_TOT + gb)*48;

    float s0 = 0.f, s1 = 0.f, sn = 0.f;
    #pragma unroll
    for (int k = 0; k < 16; ++k) {
        float bk = bkey[k];
        s0 += q[k]*(kv0[k] + bk);
        s1 += q[k]*(kv1[k] + bk);
        sn += q[k]*bk;
    }
    s0 *= 0.25f; s1 *= 0.25f; sn *= 0.25f;

    float mx = fmaxf(s0, fmaxf(s1, sn));
    float e0 = expf(s0-mx), e1 = expf(s1-mx), en = expf(sn-mx);
    float inv = 1.f/(e0+e1+en);
    float p0 = e0*inv, p1 = e1*inv, pn = en*inv;

    int rank = 0;
    #pragma unroll
    for (int m = 0; m < 8; ++m) {
        float sm = __shfl(sn, (l & ~7) + m, 64);
        if (sm > sn || (sm == sn && m < n)) rank++;
    }
    float mk = (rank < 4) ? 0.f : 1.f;
    maskf[(size_t)gb*8 + n] = mk;

    unsigned short* op = inputs + ((size_t)n*B_TOT + gb)*32;
    #pragma unroll
    for (int db = 0; db < 4; ++db) {
        bf16x8 o;
        #pragma unroll
        for (int e = 0; e < 8; ++e) {
            int d = db*8 + e;
            float bv = bval[d];
            float v = mk*(p0*(kv0[16+d]+bv) + p1*(kv1[16+d]+bv) + pn*bv);
            o[e] = (short)f2bf(v);
        }
        *(bf16x8*)&op[db*8] = o;
    }
}

// ---------- per-batch 4-head attention; 4 batches/block; ctx in-place over v2 ----------
__global__ __launch_bounds__(256) void attn_kernel(
    unsigned short* __restrict__ QKV, const float* __restrict__ maskf, int Bc, int c0)
{
    int wid = threadIdx.x >> 6;
    int l   = threadIdx.x & 63;
    int b   = blockIdx.x*4 + wid;
    int gb  = c0 + b;

    __shared__ float qk[4][8][64];
    __shared__ float P[4][4][8][8];

    for (int it = 0; it < 8; ++it) {
        int idx = l + 64*it;
        int n = idx >> 6, c = idx & 63;
        qk[wid][n][c] = bf2f(QKV[((size_t)n*Bc + b)*1152 + c]);
    }
    __syncthreads();

    for (int it = 0; it < 4; ++it) {
        int idx = l + 64*it;
        int h = idx >> 6, n = (idx >> 3) & 7, m = idx & 7;
        float s = 0.f;
        #pragma unroll
        for (int dk = 0; dk < 8; ++dk) s += qk[wid][n][h*8 + dk]*qk[wid][m][32 + h*8 + dk];
        P[wid][h][n][m] = s * 0.35355339059327373f;
    }
    __syncthreads();

    if (l < 32) {
        int h = l >> 3, n = l & 7;
        float mx = -1e30f;
        for (int m = 0; m < 8; ++m) mx = fmaxf(mx, P[wid][h][n][m]);
        float e[8], sum = 0.f;
        for (int m = 0; m < 8; ++m) { e[m] = expf(P[wid][h][n][m]-mx); sum += e[m]; }
        float scl = maskf[(size_t)gb*8 + n] / sum;
        for (int m = 0; m < 8; ++m) P[wid][h][n][m] = e[m]*scl;
    }
    __syncthreads();

    #pragma unroll
    for (int it = 0; it < 2; ++it) {
        int colb = (l + 64*it)*8;
        int h = colb >> 8;
        float acc[8][8];
        #pragma unroll
        for (int n = 0; n < 8; ++n)
            #pragma unroll
            for (int c = 0; c < 8; ++c) acc[n][c] = 0.f;
        for (int m = 0; m < 8; ++m) {
            bf16x8 v8 = *(const bf16x8*)&QKV[((size_t)m*Bc + b)*1152 + 64 + colb];
            float vf[8];
            #pragma unroll
            for (int c = 0; c < 8; ++c) vf[c] = bf2f((unsigned short)v8[c]);
            #pragma unroll
            for (int n = 0; n < 8; ++n) {
                float p = P[wid][h][n][m];
                #pragma unroll
                for (int c = 0; c < 8; ++c) acc[n][c] += p*vf[c];
            }
        }
        #pragma unroll
        for (int n = 0; n < 8; ++n) {
            bf16x8 o;
            #pragma unroll
            for (int c = 0; c < 8; ++c) o[c] = (short)f2bf(acc[n][c]);
            *(bf16x8*)&QKV[((size_t)n*Bc + b)*1152 + 64 + colb] = o;
        }
    }
}

// ---------- MFMA GEMM: dbuf LDS + 2-deep register prefetch, n->XCD, col-fastest ----
// MODE 0: gates+GRU fused (A = hsb|inputs). MODE 1: qkv. MODE 2: out + epilogue.
template<int MODE>
__global__ __launch_bounds__(256) void gemm_mfma(
    const float* __restrict__ hs_glob,
    const unsigned short* __restrict__ hsb,
    const unsigned short* __restrict__ inputs,
    const unsigned short* __restrict__ Asrc,
    const unsigned short* __restrict__ Wp,
    unsigned short* __restrict__ hsnb,
    unsigned short* __restrict__ QKV,
    const float* __restrict__ maskf,
    float* __restrict__ outp,
    int Bc, int c0)
{
    constexpr int KW   = (MODE==0) ? 288 : (MODE==1 ? 256 : 1024);
    constexpr int M    = (MODE==0) ? 1024 : (MODE==1 ? 1152 : 256);
    constexpr int TN   = 128;
    constexpr int NJ   = TN/16;      // 8
    constexpr int NT   = KW/32;
    constexpr int ASTR = (MODE==2) ? 1152 : 256;
    constexpr int CB   = M/TN;

    int bid = blockIdx.x;
    int n   = bid & 7;                 // unit == XCD: W panel stays in one L2
    int loc = bid >> 3;
    int col0 = (loc % CB) * TN;        // cols fastest: A row-tile reused in L2
    int row0 = (loc / CB) * 128;

    __shared__ unsigned short As[2][128*32];
    __shared__ unsigned short Ws[2][TN*32];

    int t = threadIdx.x;
    int l = t & 63, w = t >> 6;
    int lr = l & 15, lk = l >> 4;

    int arow = t >> 1, aseg = t & 1;   // A staging: 128 rows x 2 k-halves
    int wrow = t >> 1, wkb = (t & 1) * 32;

    f32x4 acc[2][NJ];
    #pragma unroll
    for (int i = 0; i < 2; ++i)
        #pragma unroll
        for (int j = 0; j < NJ; ++j)
            acc[i][j] = (f32x4){0.f,0.f,0.f,0.f};

    // two named prefetch sets (rule #20: no runtime-indexed reg arrays)
    bf16x8 aA0, aA1, wA0, wA1;
    bf16x8 aB0, aB1, wB0, wB1;

    auto loadA = [&](int k0, bf16x8 &u0, bf16x8 &u1) {
        const unsigned short* s;
        if (MODE == 0) {
            if (k0 < 256) s = hsb + ((size_t)n*B_TOT + c0 + row0 + arow)*256 + k0 + aseg*16;
            else          s = inputs + ((size_t)n*B_TOT + c0 + row0 + arow)*32 + aseg*16;
        } else {
            s = Asrc + ((size_t)n*Bc + row0 + arow)*ASTR + k0 + aseg*16;
        }
        u0 = ((const bf16x8*)s)[0];
        u1 = ((const bf16x8*)s)[1];
    };
    auto loadW = [&](int k0, bf16x8 &u0, bf16x8 &u1) {
        const unsigned short* s = Wp + ((size_t)n*M + col0 + wrow)*(size_t)KW + k0 + (wkb >> 1);
        u0 = ((const bf16x8*)s)[0];
        u1 = ((const bf16x8*)s)[1];
    };
    auto stage = [&](char* A_, char* W_, bf16x8 a0, bf16x8 a1, bf16x8 w0, bf16x8 w1) {
        *(bf16x8*)(A_ + swz(arow, aseg*32))      = a0;
        *(bf16x8*)(A_ + swz(arow, aseg*32 + 16)) = a1;
        *(bf16x8*)(W_ + swz(wrow, wkb))          = w0;
        *(bf16x8*)(W_ + swz(wrow, wkb + 16))     = w1;
    };
    auto compute = [&](char* A_, char* W_) {
        bf16x8 a0 = *(bf16x8*)(A_ + swz(w*32 + lr,      lk*16));
        bf16x8 a1 = *(bf16x8*)(A_ + swz(w*32 + 16 + lr, lk*16));
        #pragma unroll
        for (int j = 0; j < NJ; ++j) {
            bf16x8 b = *(bf16x8*)(W_ + swz(j*16 + lr, lk*16));
            acc[0][j] = __builtin_amdgcn_mfma_f32_16x16x32_bf16(a0, b, acc[0][j], 0, 0, 0);
            acc[1][j] = __builtin_amdgcn_mfma_f32_16x16x32_bf16(a1, b, acc[1][j], 0, 0, 0);
        }
    };

    char* AE = (char*)&As[0][0]; char* AO = (char*)&As[1][0];
    char* WE = (char*)&Ws[0][0]; char* WO = (char*)&Ws[1][0];

    loadA(0,  aA0, aA1);  loadW(0,  wA0, wA1);
    loadA(32, aB0, aB1);  loadW(32, wB0, wB1);

    int tt = 0;
    for (; tt + 1 < NT; tt += 2) {
        stage(AE, WE, aA0, aA1, wA0, wA1);
        __syncthreads();
        if (tt + 2 < NT) { loadA((tt+2)*32, aA0, aA1); loadW((tt+2)*32, wA0, wA1); }
        compute(AE, WE);

        stage(AO, WO, aB0, aB1, wB0, wB1);
        __syncthreads();
        if (tt + 3 < NT) { loadA((tt+3)*32, aB0, aB1); loadW((tt+3)*32, wB0, wB1); }
        compute(AO, WO);
    }
    if (tt < NT) {            // odd NT (MODE 0: NT=9) — trailing tile in set A
        stage(AE, WE, aA0, aA1, wA0, wA1);
        __syncthreads();
        compute(AE, WE);
    }

    if constexpr (MODE == 0) {
        #pragma unroll
        for (int i = 0; i < 2; ++i) {
            int rbase = row0 + w*32 + i*16 + lk*4;
            #pragma unroll
            for (int half = 0; half < 2; ++half) {
                int o = (col0 >> 2) + half*16 + lr;
                #pragma unroll
                for (int reg = 0; reg < 4; ++reg) {
                    int r = rbase + reg;
                    float rs = acc[i][0+half][reg];
                    float zs = acc[i][2+half][reg];
                    float gx = acc[i][4+half][reg];
                    float gh = acc[i][6+half][reg];
                    float hold = bf2f(hsb[((size_t)n*B_TOT + c0 + r)*256 + o]);
                    float rr = sigm(rs), z = sigm(zs);
                    float nn = tanhf(gx + rr*gh);
                    float h  = nn + z*(hold - nn);
                    hsnb[((size_t)n*Bc + r)*256 + o] = f2bf(h);
                }
            }
        }
    } else if constexpr (MODE == 1) {
        #pragma unroll
        for (int i = 0; i < 2; ++i) {
            #pragma unroll
            for (int j = 0; j < NJ; ++j) {
                int c = col0 + j*16 + lr;
                #pragma unroll
                for (int reg = 0; reg < 4; ++reg) {
                    int r = row0 + w*32 + i*16 + lk*4 + reg;
                    QKV[((size_t)n*Bc + r)*1152 + c] = f2bf(acc[i][j][reg]);
                }
            }
        }
    } else {
        #pragma unroll
        for (int i = 0; i < 2; ++i) {
            #pragma unroll
            for (int reg = 0; reg < 4; ++reg) {
                int r = row0 + w*32 + i*16 + lk*4 + reg;
                float mkv = maskf[(size_t)(c0 + r)*8 + n];
                #pragma unroll
                for (int j = 0; j < NJ; ++j) {
                    int c = col0 + j*16 + lr;
                    size_t gi = (((size_t)(c0 + r))*NU + n)*HH + c;
                    float v;
                    if (mkv != 0.f) v = acc[i][j][reg] + bf2f(hsnb[((size_t)n*Bc + r)*256 + c]);
                    else            v = hs_glob[gi];
                    outp[gi] = v;
                }
            }
        }
    }
}

extern "C" void kernel_launch(void* const* d_in, const int* in_sizes, int n_in,
                              void* d_out, int out_size, void* d_ws, size_t ws_size,
                              hipStream_t stream)
{
    const float* x1   = (const float*)d_in[0];
    const float* x2   = (const float*)d_in[1];
    const float* hs   = (const float*)d_in[2];
    const float* Wkey = (const float*)d_in[3];
    const float* bkey = (const float*)d_in[4];
    const float* Wval = (const float*)d_in[5];
    const float* bval = (const float*)d_in[6];
    const float* Wq   = (const float*)d_in[7];
    const float* Wq_  = (const float*)d_in[8];
    const float* Wk_  = (const float*)d_in[9];
    const float* Wv_  = (const float*)d_in[10];
    const float* Wout = (const float*)d_in[11];
    const float* Wx2h = (const float*)d_in[12];
    const float* Wh2h = (const float*)d_in[13];
    float* out = (float*)d_out;

    char* ws = (char*)d_ws;
    size_t off = 0;
    auto alloc = [&](size_t bytes) -> void* {
        void* p = (void*)(ws + off);
        off = (off + bytes + 255) & ~(size_t)255;
        return p;
    };
    unsigned short* Wg     = (unsigned short*)alloc((size_t)8*1024*288*2);
    unsigned short* Wqkv   = (unsigned short*)alloc((size_t)8*1152*256*2);
    unsigned short* WoutT  = (unsigned short*)alloc((size_t)8*256*1024*2);
    unsigned short* Wkv    = (unsigned short*)alloc((size_t)48*256*2);
    unsigned short* Wqt    = (unsigned short*)alloc((size_t)8*16*256*2);
    unsigned short* inputs = (unsigned short*)alloc((size_t)8*B_TOT*32*2);
    float*          maskf  = (float*)         alloc((size_t)B_TOT*8*4);
    float*          KV     = (float*)         alloc((size_t)2*B_TOT*48*4);
    float*          qL     = (float*)         alloc((size_t)8*B_TOT*16*4);
    unsigned short* hsb    = (unsigned short*)alloc((size_t)8*B_TOT*256*2);
    size_t persist = off;

    const size_t perB = 8*256*2 + 8*1152*2;   // hsnb + QKV
    // Bc=4096: per-chunk QKV (75MB) + hsnb (17MB) + weights stays L3-resident,
    // and ws addresses are reused next chunk (write hits, no HBM round-trip).
    int Bc = 4096;
    while (Bc > 128 && persist + (size_t)Bc*perB + 65536 > ws_size) Bc >>= 1;
    unsigned short* hsnb = (unsigned short*)alloc((size_t)8*Bc*256*2);
    unsigned short* QKV  = (unsigned short*)alloc((size_t)8*Bc*1152*2);

    pack_gates<<<(8*1024*288 + 255)/256, 256, 0, stream>>>(Wh2h, Wx2h, Wg);
    pack_qkv  <<<(8*1152*256 + 255)/256, 256, 0, stream>>>(Wq_, Wk_, Wv_, Wqkv);
    pack_out  <<<(8*256*1024 + 255)/256, 256, 0, stream>>>(Wout, WoutT);
    pack_kvw  <<<(48*256 + 255)/256, 256, 0, stream>>>(Wkey, Wval, Wkv);
    pack_qlw  <<<(8*16*256 + 255)/256, 256, 0, stream>>>(Wq, Wqt);

    small_gemm<0><<<dim3(2*B_TOT/128), 256, 0, stream>>>(x1, x2, Wkv, KV, nullptr);
    small_gemm<1><<<dim3(B_TOT/128, 8), 256, 0, stream>>>(hs, nullptr, Wqt, qL, hsb);
    score_mask_inputs<<<B_TOT/32, 256, 0, stream>>>(KV, qL, bkey, bval, inputs, maskf);

    for (int c0 = 0; c0 < B_TOT; c0 += Bc) {
        int RB = Bc / 128;
        gemm_mfma<0><<<dim3(RB*8*8), 256, 0, stream>>>(
            hs, hsb, inputs, nullptr, Wg, hsnb, nullptr, nullptr, nullptr, Bc, c0);
        gemm_mfma<1><<<dim3(RB*9*8), 256, 0, stream>>>(
            hs, hsb, nullptr, hsnb, Wqkv, nullptr, QKV, nullptr, nullptr, Bc, c0);
        attn_kernel<<<Bc/4, 256, 0, stream>>>(QKV, maskf, Bc, c0);
        gemm_mfma<2><<<dim3(RB*2*8), 256, 0, stream>>>(
            hs, hsb, nullptr, QKV + 64, WoutT, hsnb, nullptr, maskf, out, Bc, c0);
    }
}